// Round 6
// baseline (468.496 us; speedup 1.0000x reference)
//
#include <hip/hip_runtime.h>
#include <hip/hip_bf16.h>
#include <hip/hip_fp16.h>

typedef __attribute__((ext_vector_type(8))) short bf16x8;
typedef __attribute__((ext_vector_type(8))) short short8;
typedef __attribute__((ext_vector_type(4))) float f32x4;

__device__ __forceinline__ unsigned short bf16_rne(float f) {
  unsigned u = __builtin_bit_cast(unsigned, f);
  unsigned r = u + 0x7fffu + ((u >> 16) & 1u);
  return (unsigned short)(r >> 16);
}
__device__ __forceinline__ float bf16_to_f32(unsigned short h) {
  return __builtin_bit_cast(float, (unsigned)h << 16);
}

// ---------------- CSR build ----------------

// hist: 4 edges/thread, vectorized dst loads, fire-and-forget atomics.
__global__ void k_hist4(const int* __restrict__ dst, int* __restrict__ cnt, int nE) {
  int e0 = (blockIdx.x * blockDim.x + threadIdx.x) * 4;
  if (e0 >= nE) return;
  if (e0 + 4 <= nE) {
    int4 d = *(const int4*)(dst + e0);
    atomicAdd(&cnt[d.x], 1);
    atomicAdd(&cnt[d.y], 1);
    atomicAdd(&cnt[d.z], 1);
    atomicAdd(&cnt[d.w], 1);
  } else {
    for (int e = e0; e < nE; e++) atomicAdd(&cnt[dst[e]], 1);
  }
}

// ---- 3-phase exclusive scan of cnt[N] -> rowptr[N] (+cursor copy, +dinv fused) ----

__global__ void k_blocksum(const int* __restrict__ cnt, int* __restrict__ bsum, int n) {
  __shared__ int red[256];
  int tid = threadIdx.x;
  int base = blockIdx.x * 1024 + tid * 4;
  int s = 0;
#pragma unroll
  for (int i = 0; i < 4; i++) { int idx = base + i; if (idx < n) s += cnt[idx]; }
  red[tid] = s;
  __syncthreads();
  for (int off = 128; off > 0; off >>= 1) {
    if (tid < off) red[tid] += red[tid + off];
    __syncthreads();
  }
  if (tid == 0) bsum[blockIdx.x] = red[0];
}

__global__ void k_scan_bsum(int* __restrict__ bsum, int nb) {
  __shared__ int s[128];
  int tid = threadIdx.x;
  int v = (tid < nb) ? bsum[tid] : 0;
  s[tid] = v;
  __syncthreads();
  for (int off = 1; off < 128; off <<= 1) {
    int t = (tid >= off) ? s[tid - off] : 0;
    __syncthreads();
    s[tid] += t;
    __syncthreads();
  }
  if (tid < nb) bsum[tid] = s[tid] - v;  // exclusive
}

__global__ void k_scan_final(const int* __restrict__ cnt, const int* __restrict__ bsum,
                             int* __restrict__ rowptr, int* __restrict__ cursor,
                             float* __restrict__ dinv, int n) {
  __shared__ int tsum[256];
  int tid = threadIdx.x;
  int base = blockIdx.x * 1024 + tid * 4;
  int v[4]; int s = 0;
#pragma unroll
  for (int i = 0; i < 4; i++) { v[i] = (base + i < n) ? cnt[base + i] : 0; s += v[i]; }
  tsum[tid] = s;
  __syncthreads();
  for (int off = 1; off < 256; off <<= 1) {
    int t = (tid >= off) ? tsum[tid - off] : 0;
    __syncthreads();
    tsum[tid] += t;
    __syncthreads();
  }
  int run = bsum[blockIdx.x] + tsum[tid] - s;  // exclusive prefix at first elem
#pragma unroll
  for (int i = 0; i < 4; i++) {
    int idx = base + i;
    if (idx < n) {
      rowptr[idx] = run;
      cursor[idx] = run;
      dinv[idx] = rsqrtf((float)(v[i] + 1));  // fused: +1 self-loop
      run += v[i];
    }
  }
}

// place: 4 edges/thread — 4 independent atomic->store chains in flight per thread.
__global__ void k_place4(const int* __restrict__ src, const int* __restrict__ dst,
                         int* __restrict__ cursor, int* __restrict__ col, int nE) {
  int e0 = (blockIdx.x * blockDim.x + threadIdx.x) * 4;
  if (e0 >= nE) return;
  if (e0 + 4 <= nE) {
    int4 s = *(const int4*)(src + e0);
    int4 d = *(const int4*)(dst + e0);
    int p0 = atomicAdd(&cursor[d.x], 1);
    int p1 = atomicAdd(&cursor[d.y], 1);
    int p2 = atomicAdd(&cursor[d.z], 1);
    int p3 = atomicAdd(&cursor[d.w], 1);
    col[p0] = s.x;
    col[p1] = s.y;
    col[p2] = s.z;
    col[p3] = s.w;
  } else {
    for (int e = e0; e < nE; e++) {
      int pos = atomicAdd(&cursor[dst[e]], 1);
      col[pos] = src[e];
    }
  }
}

// ---- weight prep: split-bf16 + transpose; fuse Wmu|Wls, bmu|bls ----

__global__ void k_prep_w(const float* __restrict__ W1,
                         const float* __restrict__ Wmu, const float* __restrict__ Wls,
                         const float* __restrict__ bmu, const float* __restrict__ bls,
                         unsigned short* __restrict__ W1Th, unsigned short* __restrict__ W1Tl,
                         unsigned short* __restrict__ WcTh, unsigned short* __restrict__ WcTl,
                         float* __restrict__ bcat) {
  int i = blockIdx.x * blockDim.x + threadIdx.x;
  if (i < 128 * 256) {                     // W1T [n][k]
    int n = i >> 8, k = i & 255;
    float f = W1[k * 128 + n];
    unsigned short hi = bf16_rne(f);
    W1Th[i] = hi;
    W1Tl[i] = bf16_rne(f - bf16_to_f32(hi));
  } else if (i < 2 * 128 * 256) {          // WcatT [n][k]
    int j = i - 128 * 256;
    int n = j >> 7, k = j & 127;
    float f = (n < 128) ? Wmu[k * 128 + n] : Wls[k * 128 + (n - 128)];
    unsigned short hi = bf16_rne(f);
    WcTh[j] = hi;
    WcTl[j] = bf16_rne(f - bf16_to_f32(hi));
  } else if (i < 2 * 128 * 256 + 256) {    // bcat
    int n = i - 2 * 128 * 256;
    bcat[n] = (n < 128) ? bmu[n] : bls[n - 128];
  }
}

// ---------------- MFMA GEMM ----------------
// Split-precision: A = Ah+Al (bf16), W pre-split WTh/WTl transposed [N][K].
// acc = Ah*Wh + Ah*Wl + Al*Wh. AFMT: 0=f32 A, 1=fp16 A. OFMT: 0=f32 out, 1=fp16 out.

#define LP 40  // LDS row stride in bf16 elems

template <int AFMT, int OFMT>
__global__ __launch_bounds__(256) void k_gemm_mfma(
    const void* __restrict__ Av,
    const unsigned short* __restrict__ WTh, const unsigned short* __restrict__ WTl,
    const float* __restrict__ bias, void* __restrict__ out0, void* __restrict__ out1,
    int M, int K, int split_out) {
  __shared__ unsigned short Ah[128 * LP];
  __shared__ unsigned short Al[128 * LP];
  __shared__ unsigned short Bh[128 * LP];
  __shared__ unsigned short Bl[128 * LP];

  const int tid = threadIdx.x;
  const int lane = tid & 63;
  const int wv = tid >> 6;
  const int wr = wv >> 1, wc = wv & 1;   // 2x2 waves, each 64x64
  const int rsel = lane >> 4;            // 0..3
  const int rrow = lane & 15;
  const int row0 = blockIdx.x * 128;
  const int col0 = blockIdx.y * 128;

  f32x4 acc[4][4];
#pragma unroll
  for (int m = 0; m < 4; m++)
#pragma unroll
    for (int n = 0; n < 4; n++) acc[m][n] = (f32x4){0.f, 0.f, 0.f, 0.f};

  const int srow = tid >> 1;            // staging row 0..127
  const int skh = (tid & 1) * 16;       // k-half 0 or 16

  for (int k0 = 0; k0 < K; k0 += 32) {
    // ---- stage A tile -> split bf16 ----
    if (row0 + srow < M) {
      float fv[16];
      if (AFMT == 0) {
        const float* src = (const float*)Av + (size_t)(row0 + srow) * K + k0 + skh;
        float4 f0 = *(const float4*)(src);
        float4 f1 = *(const float4*)(src + 4);
        float4 f2 = *(const float4*)(src + 8);
        float4 f3 = *(const float4*)(src + 12);
        fv[0]=f0.x; fv[1]=f0.y; fv[2]=f0.z; fv[3]=f0.w;
        fv[4]=f1.x; fv[5]=f1.y; fv[6]=f1.z; fv[7]=f1.w;
        fv[8]=f2.x; fv[9]=f2.y; fv[10]=f2.z; fv[11]=f2.w;
        fv[12]=f3.x; fv[13]=f3.y; fv[14]=f3.z; fv[15]=f3.w;
      } else {
        const __half* src = (const __half*)Av + (size_t)(row0 + srow) * K + k0 + skh;
        short8 r0 = *(const short8*)(src);
        short8 r1 = *(const short8*)(src + 8);
#pragma unroll
        for (int j = 0; j < 8; j++) {
          fv[j]     = __half2float(__builtin_bit_cast(__half, (unsigned short)r0[j]));
          fv[8 + j] = __half2float(__builtin_bit_cast(__half, (unsigned short)r1[j]));
        }
      }
      bf16x8 vh0, vl0, vh1, vl1;
#pragma unroll
      for (int j = 0; j < 8; j++) {
        unsigned short hi = bf16_rne(fv[j]);
        vh0[j] = (short)hi;
        vl0[j] = (short)bf16_rne(fv[j] - bf16_to_f32(hi));
        unsigned short hi2 = bf16_rne(fv[8 + j]);
        vh1[j] = (short)hi2;
        vl1[j] = (short)bf16_rne(fv[8 + j] - bf16_to_f32(hi2));
      }
      *(bf16x8*)&Ah[srow * LP + skh]     = vh0;
      *(bf16x8*)&Ah[srow * LP + skh + 8] = vh1;
      *(bf16x8*)&Al[srow * LP + skh]     = vl0;
      *(bf16x8*)&Al[srow * LP + skh + 8] = vl1;
    } else {
      bf16x8 z = (bf16x8){0,0,0,0,0,0,0,0};
      *(bf16x8*)&Ah[srow * LP + skh] = z; *(bf16x8*)&Ah[srow * LP + skh + 8] = z;
      *(bf16x8*)&Al[srow * LP + skh] = z; *(bf16x8*)&Al[srow * LP + skh + 8] = z;
    }
    // ---- stage W tile ----
    {
      const unsigned short* sh = WTh + (size_t)(col0 + srow) * K + k0 + skh;
      const unsigned short* sl = WTl + (size_t)(col0 + srow) * K + k0 + skh;
      *(bf16x8*)&Bh[srow * LP + skh]     = *(const bf16x8*)sh;
      *(bf16x8*)&Bh[srow * LP + skh + 8] = *(const bf16x8*)(sh + 8);
      *(bf16x8*)&Bl[srow * LP + skh]     = *(const bf16x8*)sl;
      *(bf16x8*)&Bl[srow * LP + skh + 8] = *(const bf16x8*)(sl + 8);
    }
    __syncthreads();

    bf16x8 fah[4], fal[4], fbh[4], fbl[4];
#pragma unroll
    for (int m = 0; m < 4; m++) {
      int off = (wr * 64 + m * 16 + rrow) * LP + rsel * 8;
      fah[m] = *(bf16x8*)&Ah[off];
      fal[m] = *(bf16x8*)&Al[off];
    }
#pragma unroll
    for (int n = 0; n < 4; n++) {
      int off = (wc * 64 + n * 16 + rrow) * LP + rsel * 8;
      fbh[n] = *(bf16x8*)&Bh[off];
      fbl[n] = *(bf16x8*)&Bl[off];
    }
#pragma unroll
    for (int m = 0; m < 4; m++)
#pragma unroll
      for (int n = 0; n < 4; n++) {
        acc[m][n] = __builtin_amdgcn_mfma_f32_16x16x32_bf16(fah[m], fbh[n], acc[m][n], 0, 0, 0);
        acc[m][n] = __builtin_amdgcn_mfma_f32_16x16x32_bf16(fah[m], fbl[n], acc[m][n], 0, 0, 0);
        acc[m][n] = __builtin_amdgcn_mfma_f32_16x16x32_bf16(fal[m], fbh[n], acc[m][n], 0, 0, 0);
      }
    __syncthreads();
  }

  // ---- epilogue: D col=lane&15, row=4*(lane>>4)+reg ----
#pragma unroll
  for (int n = 0; n < 4; n++) {
    int col = col0 + wc * 64 + n * 16 + rrow;
    float badd = bias ? bias[col] : 0.f;
    void* dstBase = out0;
    int c = col;
    if (split_out && c >= 128) { dstBase = out1; c -= 128; }
#pragma unroll
    for (int m = 0; m < 4; m++) {
      f32x4 v = acc[m][n];
#pragma unroll
      for (int r = 0; r < 4; r++) {
        int row = row0 + wr * 64 + m * 16 + rsel * 4 + r;
        if (row < M) {
          if (OFMT == 0)
            ((float*)dstBase)[(size_t)row * 128 + c] = v[r] + badd;
          else
            ((__half*)dstBase)[(size_t)row * 128 + c] = __float2half(v[r] + badd);
        }
      }
    }
  }
}

// ---------------- pull-based SpMM (fp16 rows, on-the-fly norm) ----------------
// out[node] = relu?( dinv[node] * ( dinv[node]*in[node] + sum_e dinv[col]*in[col] ) + bias )

__global__ __launch_bounds__(256) void k_spmm_h(
    const __half* __restrict__ in, const int* __restrict__ rowptr,
    const int* __restrict__ cnt, const int* __restrict__ col,
    const float* __restrict__ dinv,
    const float* __restrict__ bias, __half* __restrict__ out,
    int n, int use_bias, int relu_out) {
  int node = blockIdx.x * 4 + (threadIdx.x >> 6);
  if (node >= n) return;
  int lane = threadIdx.x & 63;

  float di = dinv[node];
  float2 v = __half22float2(((const __half2*)(in + (size_t)node * 128))[lane]);
  float accx = di * v.x;
  float accy = di * v.y;

  int beg = rowptr[node];
  int m = cnt[node];
  int i = 0;
  for (; i + 4 <= m; i += 4) {
    int c0 = col[beg + i], c1 = col[beg + i + 1], c2 = col[beg + i + 2], c3 = col[beg + i + 3];
    float e0 = dinv[c0], e1 = dinv[c1], e2 = dinv[c2], e3 = dinv[c3];
    float2 u0 = __half22float2(((const __half2*)(in + (size_t)c0 * 128))[lane]);
    float2 u1 = __half22float2(((const __half2*)(in + (size_t)c1 * 128))[lane]);
    float2 u2 = __half22float2(((const __half2*)(in + (size_t)c2 * 128))[lane]);
    float2 u3 = __half22float2(((const __half2*)(in + (size_t)c3 * 128))[lane]);
    accx += e0 * u0.x + e1 * u1.x + e2 * u2.x + e3 * u3.x;
    accy += e0 * u0.y + e1 * u1.y + e2 * u2.y + e3 * u3.y;
  }
  for (; i < m; i++) {
    int c0 = col[beg + i];
    float e0 = dinv[c0];
    float2 u0 = __half22float2(((const __half2*)(in + (size_t)c0 * 128))[lane]);
    accx += e0 * u0.x;
    accy += e0 * u0.y;
  }
  accx *= di;
  accy *= di;
  if (use_bias) {
    accx += bias[2 * lane];
    accy += bias[2 * lane + 1];
  }
  if (relu_out) {
    accx = fmaxf(accx, 0.f);
    accy = fmaxf(accy, 0.f);
  }
  ((__half2*)(out + (size_t)node * 128))[lane] = __floats2half2_rn(accx, accy);
}

// ---------------- launch ----------------

extern "C" void kernel_launch(void* const* d_in, const int* in_sizes, int n_in,
                              void* d_out, int out_size, void* d_ws, size_t ws_size,
                              hipStream_t stream) {
  const float* x   = (const float*)d_in[0];
  const int*   ei  = (const int*)d_in[1];
  const float* W1  = (const float*)d_in[2];
  const float* b1  = (const float*)d_in[3];
  const float* Wmu = (const float*)d_in[4];
  const float* bmu = (const float*)d_in[5];
  const float* Wls = (const float*)d_in[6];
  const float* bls = (const float*)d_in[7];

  int N = in_sizes[0] / 256;
  int E = in_sizes[1] / 2;
  const int* src = ei;
  const int* dst = ei + E;

  char* ws = (char*)d_ws;
  size_t o = 0;
  auto alloc = [&](size_t b) { size_t c = o; o = (o + b + 511) & ~(size_t)511; return c; };
  int*   cnt    = (int*)(ws + alloc((size_t)N * 4));
  int*   rowptr = (int*)(ws + alloc((size_t)N * 4));
  int*   cursor = (int*)(ws + alloc((size_t)N * 4));
  int*   bsum   = (int*)(ws + alloc(512));
  float* dinv   = (float*)(ws + alloc((size_t)N * 4));
  int*   col    = (int*)(ws + alloc((size_t)E * 4));
  unsigned short* W1Th = (unsigned short*)(ws + alloc(128 * 256 * 2));
  unsigned short* W1Tl = (unsigned short*)(ws + alloc(128 * 256 * 2));
  unsigned short* WcTh = (unsigned short*)(ws + alloc(256 * 128 * 2));
  unsigned short* WcTl = (unsigned short*)(ws + alloc(256 * 128 * 2));
  float*  bcat = (float*)(ws + alloc(256 * 4));
  __half* h0   = (__half*)(ws + alloc((size_t)N * 128 * 2));  // GEMM1 out, later g
  __half* hBuf = (__half*)(ws + alloc((size_t)N * 128 * 2));  // h (relu'd)

  float* outMu = (float*)d_out;
  float* outLs = outMu + (size_t)N * 128;

  int nbScan = (N + 1023) / 1024;

  hipMemsetAsync(cnt, 0, (size_t)N * 4, stream);
  k_hist4<<<(E / 4 + 255) / 256, 256, 0, stream>>>(dst, cnt, E);
  k_blocksum<<<nbScan, 256, 0, stream>>>(cnt, bsum, N);
  k_scan_bsum<<<1, 128, 0, stream>>>(bsum, nbScan);
  k_scan_final<<<nbScan, 256, 0, stream>>>(cnt, bsum, rowptr, cursor, dinv, N);
  k_place4<<<(E / 4 + 255) / 256, 256, 0, stream>>>(src, dst, cursor, col, E);
  k_prep_w<<<(2 * 128 * 256 + 256 + 255) / 256, 256, 0, stream>>>(
      W1, Wmu, Wls, bmu, bls, W1Th, W1Tl, WcTh, WcTl, bcat);

  int gx = (N + 127) / 128;
  // h0 = x @ W1                 [N,128] fp16
  k_gemm_mfma<0, 1><<<dim3(gx, 1), 256, 0, stream>>>(x, W1Th, W1Tl, nullptr, h0, nullptr, N, 256, 0);
  // h = relu(A h0 + b1)         [N,128] fp16
  k_spmm_h<<<(N + 3) / 4, 256, 0, stream>>>(h0, rowptr, cnt, col, dinv, b1, hBuf, N, 1, 1);
  // g = A h                     [N,128] fp16 (reuse h0 buffer)
  k_spmm_h<<<(N + 3) / 4, 256, 0, stream>>>(hBuf, rowptr, cnt, col, dinv, nullptr, h0, N, 0, 0);
  // [mu | ls] = g @ [Wmu|Wls] + [bmu|bls]   one fused dispatch, grid.y=2
  k_gemm_mfma<1, 0><<<dim3(gx, 2), 256, 0, stream>>>(h0, WcTh, WcTl, bcat, outMu, outLs, N, 128, 1);
}

// Round 7
// 451.475 us; speedup vs baseline: 1.0377x; 1.0377x over previous
//
#include <hip/hip_runtime.h>
#include <hip/hip_bf16.h>
#include <hip/hip_fp16.h>

typedef __attribute__((ext_vector_type(8))) short bf16x8;
typedef __attribute__((ext_vector_type(8))) short short8;
typedef __attribute__((ext_vector_type(4))) float f32x4;

__device__ __forceinline__ unsigned short bf16_rne(float f) {
  unsigned u = __builtin_bit_cast(unsigned, f);
  unsigned r = u + 0x7fffu + ((u >> 16) & 1u);
  return (unsigned short)(r >> 16);
}
__device__ __forceinline__ float bf16_to_f32(unsigned short h) {
  return __builtin_bit_cast(float, (unsigned)h << 16);
}

// ================= CSR build via coarse binning (no random-line scatter) =================
// bin = dst >> 6 (64 nodes/bin); sub-bin = bin*8 + replica, replica = threadflat & 7.
// Edge->sub-bin mapping MUST be identical in k_sub_hist and k_sub_scatter (same grid, same formula).

__global__ void k_sub_hist(const int* __restrict__ dst, int* __restrict__ subCnt, int nE) {
  int t = blockIdx.x * blockDim.x + threadIdx.x;
  int e0 = t * 4;
  if (e0 >= nE) return;
  int r = t & 7;
  if (e0 + 4 <= nE) {
    int4 d = *(const int4*)(dst + e0);
    atomicAdd(&subCnt[(d.x >> 6) * 8 + r], 1);
    atomicAdd(&subCnt[(d.y >> 6) * 8 + r], 1);
    atomicAdd(&subCnt[(d.z >> 6) * 8 + r], 1);
    atomicAdd(&subCnt[(d.w >> 6) * 8 + r], 1);
  } else {
    for (int e = e0; e < nE; e++) atomicAdd(&subCnt[(dst[e] >> 6) * 8 + r], 1);
  }
}

__global__ void k_sub_scatter(const int* __restrict__ src, const int* __restrict__ dst,
                              int* __restrict__ subCursor, int2* __restrict__ binned, int nE) {
  int t = blockIdx.x * blockDim.x + threadIdx.x;
  int e0 = t * 4;
  if (e0 >= nE) return;
  int r = t & 7;
  if (e0 + 4 <= nE) {
    int4 s = *(const int4*)(src + e0);
    int4 d = *(const int4*)(dst + e0);
    int p0 = atomicAdd(&subCursor[(d.x >> 6) * 8 + r], 1);
    int p1 = atomicAdd(&subCursor[(d.y >> 6) * 8 + r], 1);
    int p2 = atomicAdd(&subCursor[(d.z >> 6) * 8 + r], 1);
    int p3 = atomicAdd(&subCursor[(d.w >> 6) * 8 + r], 1);
    binned[p0] = make_int2(s.x, d.x);
    binned[p1] = make_int2(s.y, d.y);
    binned[p2] = make_int2(s.z, d.z);
    binned[p3] = make_int2(s.w, d.w);
  } else {
    for (int e = e0; e < nE; e++) {
      int p = atomicAdd(&subCursor[(dst[e] >> 6) * 8 + r], 1);
      binned[p] = make_int2(src[e], dst[e]);
    }
  }
}

// per-bin degree count: LDS histogram over the bin's 64 nodes, sequential store. No global atomics.
__global__ __launch_bounds__(256) void k_bin_cnt(
    const int2* __restrict__ binned, const int* __restrict__ subPtr, const int* __restrict__ subCnt,
    int* __restrict__ cnt, int n) {
  __shared__ int c64[64];
  int b = blockIdx.x;
  int tid = threadIdx.x;
  if (tid < 64) c64[tid] = 0;
  __syncthreads();
  int start = subPtr[b * 8];
  int end = subPtr[b * 8 + 7] + subCnt[b * 8 + 7];
  for (int i = start + tid; i < end; i += 256)
    atomicAdd(&c64[binned[i].y & 63], 1);
  __syncthreads();
  if (tid < 64) {
    int idx = b * 64 + tid;
    if (idx < n) cnt[idx] = c64[tid];
  }
}

// per-bin placement: LDS cursors seeded from rowptr; col writes land in the bin's dense CSR window.
__global__ __launch_bounds__(256) void k_bin_place(
    const int2* __restrict__ binned, const int* __restrict__ subPtr, const int* __restrict__ subCnt,
    const int* __restrict__ rowptr, int* __restrict__ col, int n) {
  __shared__ int cur64[64];
  int b = blockIdx.x;
  int tid = threadIdx.x;
  if (tid < 64) {
    int idx = b * 64 + tid;
    cur64[tid] = (idx < n) ? rowptr[idx] : 0;
  }
  __syncthreads();
  int start = subPtr[b * 8];
  int end = subPtr[b * 8 + 7] + subCnt[b * 8 + 7];
  for (int i = start + tid; i < end; i += 256) {
    int2 e = binned[i];
    int pos = atomicAdd(&cur64[e.y & 63], 1);
    col[pos] = e.x;
  }
}

// ---- 3-phase exclusive scan of cnt[n] -> rowptr (optional cursor copy, optional fused dinv) ----

__global__ void k_blocksum(const int* __restrict__ cnt, int* __restrict__ bsum, int n) {
  __shared__ int red[256];
  int tid = threadIdx.x;
  int base = blockIdx.x * 1024 + tid * 4;
  int s = 0;
#pragma unroll
  for (int i = 0; i < 4; i++) { int idx = base + i; if (idx < n) s += cnt[idx]; }
  red[tid] = s;
  __syncthreads();
  for (int off = 128; off > 0; off >>= 1) {
    if (tid < off) red[tid] += red[tid + off];
    __syncthreads();
  }
  if (tid == 0) bsum[blockIdx.x] = red[0];
}

__global__ void k_scan_bsum(int* __restrict__ bsum, int nb) {
  __shared__ int s[128];
  int tid = threadIdx.x;
  int v = (tid < nb) ? bsum[tid] : 0;
  s[tid] = v;
  __syncthreads();
  for (int off = 1; off < 128; off <<= 1) {
    int t = (tid >= off) ? s[tid - off] : 0;
    __syncthreads();
    s[tid] += t;
    __syncthreads();
  }
  if (tid < nb) bsum[tid] = s[tid] - v;  // exclusive
}

__global__ void k_scan_final(const int* __restrict__ cnt, const int* __restrict__ bsum,
                             int* __restrict__ rowptr, int* __restrict__ cursor,
                             float* __restrict__ dinv, int n) {
  __shared__ int tsum[256];
  int tid = threadIdx.x;
  int base = blockIdx.x * 1024 + tid * 4;
  int v[4]; int s = 0;
#pragma unroll
  for (int i = 0; i < 4; i++) { v[i] = (base + i < n) ? cnt[base + i] : 0; s += v[i]; }
  tsum[tid] = s;
  __syncthreads();
  for (int off = 1; off < 256; off <<= 1) {
    int t = (tid >= off) ? tsum[tid - off] : 0;
    __syncthreads();
    tsum[tid] += t;
    __syncthreads();
  }
  int run = bsum[blockIdx.x] + tsum[tid] - s;  // exclusive prefix at first elem
#pragma unroll
  for (int i = 0; i < 4; i++) {
    int idx = base + i;
    if (idx < n) {
      rowptr[idx] = run;
      if (cursor) cursor[idx] = run;
      if (dinv) dinv[idx] = rsqrtf((float)(v[i] + 1));  // +1 self-loop
      run += v[i];
    }
  }
}

// ---- weight prep: split-bf16 + transpose; fuse Wmu|Wls, bmu|bls ----

__global__ void k_prep_w(const float* __restrict__ W1,
                         const float* __restrict__ Wmu, const float* __restrict__ Wls,
                         const float* __restrict__ bmu, const float* __restrict__ bls,
                         unsigned short* __restrict__ W1Th, unsigned short* __restrict__ W1Tl,
                         unsigned short* __restrict__ WcTh, unsigned short* __restrict__ WcTl,
                         float* __restrict__ bcat) {
  int i = blockIdx.x * blockDim.x + threadIdx.x;
  if (i < 128 * 256) {                     // W1T [n][k]
    int n = i >> 8, k = i & 255;
    float f = W1[k * 128 + n];
    unsigned short hi = bf16_rne(f);
    W1Th[i] = hi;
    W1Tl[i] = bf16_rne(f - bf16_to_f32(hi));
  } else if (i < 2 * 128 * 256) {          // WcatT [n][k]
    int j = i - 128 * 256;
    int n = j >> 7, k = j & 127;
    float f = (n < 128) ? Wmu[k * 128 + n] : Wls[k * 128 + (n - 128)];
    unsigned short hi = bf16_rne(f);
    WcTh[j] = hi;
    WcTl[j] = bf16_rne(f - bf16_to_f32(hi));
  } else if (i < 2 * 128 * 256 + 256) {    // bcat
    int n = i - 2 * 128 * 256;
    bcat[n] = (n < 128) ? bmu[n] : bls[n - 128];
  }
}

// ---------------- MFMA GEMM ----------------
// Split-precision: A = Ah+Al (bf16), W pre-split WTh/WTl transposed [N][K].
// acc = Ah*Wh + Ah*Wl + Al*Wh. AFMT: 0=f32 A, 1=fp16 A. OFMT: 0=f32 out, 1=fp16 out.

#define LP 40  // LDS row stride in bf16 elems

template <int AFMT, int OFMT>
__global__ __launch_bounds__(256) void k_gemm_mfma(
    const void* __restrict__ Av,
    const unsigned short* __restrict__ WTh, const unsigned short* __restrict__ WTl,
    const float* __restrict__ bias, void* __restrict__ out0, void* __restrict__ out1,
    int M, int K, int split_out) {
  __shared__ unsigned short Ah[128 * LP];
  __shared__ unsigned short Al[128 * LP];
  __shared__ unsigned short Bh[128 * LP];
  __shared__ unsigned short Bl[128 * LP];

  const int tid = threadIdx.x;
  const int lane = tid & 63;
  const int wv = tid >> 6;
  const int wr = wv >> 1, wc = wv & 1;   // 2x2 waves, each 64x64
  const int rsel = lane >> 4;            // 0..3
  const int rrow = lane & 15;
  const int row0 = blockIdx.x * 128;
  const int col0 = blockIdx.y * 128;

  f32x4 acc[4][4];
#pragma unroll
  for (int m = 0; m < 4; m++)
#pragma unroll
    for (int n = 0; n < 4; n++) acc[m][n] = (f32x4){0.f, 0.f, 0.f, 0.f};

  const int srow = tid >> 1;            // staging row 0..127
  const int skh = (tid & 1) * 16;       // k-half 0 or 16

  for (int k0 = 0; k0 < K; k0 += 32) {
    // ---- stage A tile -> split bf16 ----
    if (row0 + srow < M) {
      float fv[16];
      if (AFMT == 0) {
        const float* src = (const float*)Av + (size_t)(row0 + srow) * K + k0 + skh;
        float4 f0 = *(const float4*)(src);
        float4 f1 = *(const float4*)(src + 4);
        float4 f2 = *(const float4*)(src + 8);
        float4 f3 = *(const float4*)(src + 12);
        fv[0]=f0.x; fv[1]=f0.y; fv[2]=f0.z; fv[3]=f0.w;
        fv[4]=f1.x; fv[5]=f1.y; fv[6]=f1.z; fv[7]=f1.w;
        fv[8]=f2.x; fv[9]=f2.y; fv[10]=f2.z; fv[11]=f2.w;
        fv[12]=f3.x; fv[13]=f3.y; fv[14]=f3.z; fv[15]=f3.w;
      } else {
        const __half* src = (const __half*)Av + (size_t)(row0 + srow) * K + k0 + skh;
        short8 r0 = *(const short8*)(src);
        short8 r1 = *(const short8*)(src + 8);
#pragma unroll
        for (int j = 0; j < 8; j++) {
          fv[j]     = __half2float(__builtin_bit_cast(__half, (unsigned short)r0[j]));
          fv[8 + j] = __half2float(__builtin_bit_cast(__half, (unsigned short)r1[j]));
        }
      }
      bf16x8 vh0, vl0, vh1, vl1;
#pragma unroll
      for (int j = 0; j < 8; j++) {
        unsigned short hi = bf16_rne(fv[j]);
        vh0[j] = (short)hi;
        vl0[j] = (short)bf16_rne(fv[j] - bf16_to_f32(hi));
        unsigned short hi2 = bf16_rne(fv[8 + j]);
        vh1[j] = (short)hi2;
        vl1[j] = (short)bf16_rne(fv[8 + j] - bf16_to_f32(hi2));
      }
      *(bf16x8*)&Ah[srow * LP + skh]     = vh0;
      *(bf16x8*)&Ah[srow * LP + skh + 8] = vh1;
      *(bf16x8*)&Al[srow * LP + skh]     = vl0;
      *(bf16x8*)&Al[srow * LP + skh + 8] = vl1;
    } else {
      bf16x8 z = (bf16x8){0,0,0,0,0,0,0,0};
      *(bf16x8*)&Ah[srow * LP + skh] = z; *(bf16x8*)&Ah[srow * LP + skh + 8] = z;
      *(bf16x8*)&Al[srow * LP + skh] = z; *(bf16x8*)&Al[srow * LP + skh + 8] = z;
    }
    // ---- stage W tile ----
    {
      const unsigned short* sh = WTh + (size_t)(col0 + srow) * K + k0 + skh;
      const unsigned short* sl = WTl + (size_t)(col0 + srow) * K + k0 + skh;
      *(bf16x8*)&Bh[srow * LP + skh]     = *(const bf16x8*)sh;
      *(bf16x8*)&Bh[srow * LP + skh + 8] = *(const bf16x8*)(sh + 8);
      *(bf16x8*)&Bl[srow * LP + skh]     = *(const bf16x8*)sl;
      *(bf16x8*)&Bl[srow * LP + skh + 8] = *(const bf16x8*)(sl + 8);
    }
    __syncthreads();

    bf16x8 fah[4], fal[4], fbh[4], fbl[4];
#pragma unroll
    for (int m = 0; m < 4; m++) {
      int off = (wr * 64 + m * 16 + rrow) * LP + rsel * 8;
      fah[m] = *(bf16x8*)&Ah[off];
      fal[m] = *(bf16x8*)&Al[off];
    }
#pragma unroll
    for (int n = 0; n < 4; n++) {
      int off = (wc * 64 + n * 16 + rrow) * LP + rsel * 8;
      fbh[n] = *(bf16x8*)&Bh[off];
      fbl[n] = *(bf16x8*)&Bl[off];
    }
#pragma unroll
    for (int m = 0; m < 4; m++)
#pragma unroll
      for (int n = 0; n < 4; n++) {
        acc[m][n] = __builtin_amdgcn_mfma_f32_16x16x32_bf16(fah[m], fbh[n], acc[m][n], 0, 0, 0);
        acc[m][n] = __builtin_amdgcn_mfma_f32_16x16x32_bf16(fah[m], fbl[n], acc[m][n], 0, 0, 0);
        acc[m][n] = __builtin_amdgcn_mfma_f32_16x16x32_bf16(fal[m], fbh[n], acc[m][n], 0, 0, 0);
      }
    __syncthreads();
  }

  // ---- epilogue: D col=lane&15, row=4*(lane>>4)+reg ----
#pragma unroll
  for (int n = 0; n < 4; n++) {
    int col = col0 + wc * 64 + n * 16 + rrow;
    float badd = bias ? bias[col] : 0.f;
    void* dstBase = out0;
    int c = col;
    if (split_out && c >= 128) { dstBase = out1; c -= 128; }
#pragma unroll
    for (int m = 0; m < 4; m++) {
      f32x4 v = acc[m][n];
#pragma unroll
      for (int r = 0; r < 4; r++) {
        int row = row0 + wr * 64 + m * 16 + rsel * 4 + r;
        if (row < M) {
          if (OFMT == 0)
            ((float*)dstBase)[(size_t)row * 128 + c] = v[r] + badd;
          else
            ((__half*)dstBase)[(size_t)row * 128 + c] = __float2half(v[r] + badd);
        }
      }
    }
  }
}

// ---------------- pull-based SpMM (fp16 rows, on-the-fly norm) ----------------
// out[node] = relu?( dinv[node] * ( dinv[node]*in[node] + sum_e dinv[col]*in[col] ) + bias )

__global__ __launch_bounds__(256) void k_spmm_h(
    const __half* __restrict__ in, const int* __restrict__ rowptr,
    const int* __restrict__ cnt, const int* __restrict__ col,
    const float* __restrict__ dinv,
    const float* __restrict__ bias, __half* __restrict__ out,
    int n, int use_bias, int relu_out) {
  int node = blockIdx.x * 4 + (threadIdx.x >> 6);
  if (node >= n) return;
  int lane = threadIdx.x & 63;

  float di = dinv[node];
  float2 v = __half22float2(((const __half2*)(in + (size_t)node * 128))[lane]);
  float accx = di * v.x;
  float accy = di * v.y;

  int beg = rowptr[node];
  int m = cnt[node];
  int i = 0;
  for (; i + 4 <= m; i += 4) {
    int c0 = col[beg + i], c1 = col[beg + i + 1], c2 = col[beg + i + 2], c3 = col[beg + i + 3];
    float e0 = dinv[c0], e1 = dinv[c1], e2 = dinv[c2], e3 = dinv[c3];
    float2 u0 = __half22float2(((const __half2*)(in + (size_t)c0 * 128))[lane]);
    float2 u1 = __half22float2(((const __half2*)(in + (size_t)c1 * 128))[lane]);
    float2 u2 = __half22float2(((const __half2*)(in + (size_t)c2 * 128))[lane]);
    float2 u3 = __half22float2(((const __half2*)(in + (size_t)c3 * 128))[lane]);
    accx += e0 * u0.x + e1 * u1.x + e2 * u2.x + e3 * u3.x;
    accy += e0 * u0.y + e1 * u1.y + e2 * u2.y + e3 * u3.y;
  }
  for (; i < m; i++) {
    int c0 = col[beg + i];
    float e0 = dinv[c0];
    float2 u0 = __half22float2(((const __half2*)(in + (size_t)c0 * 128))[lane]);
    accx += e0 * u0.x;
    accy += e0 * u0.y;
  }
  accx *= di;
  accy *= di;
  if (use_bias) {
    accx += bias[2 * lane];
    accy += bias[2 * lane + 1];
  }
  if (relu_out) {
    accx = fmaxf(accx, 0.f);
    accy = fmaxf(accy, 0.f);
  }
  ((__half2*)(out + (size_t)node * 128))[lane] = __floats2half2_rn(accx, accy);
}

// ---------------- launch ----------------

extern "C" void kernel_launch(void* const* d_in, const int* in_sizes, int n_in,
                              void* d_out, int out_size, void* d_ws, size_t ws_size,
                              hipStream_t stream) {
  const float* x   = (const float*)d_in[0];
  const int*   ei  = (const int*)d_in[1];
  const float* W1  = (const float*)d_in[2];
  const float* b1  = (const float*)d_in[3];
  const float* Wmu = (const float*)d_in[4];
  const float* bmu = (const float*)d_in[5];
  const float* Wls = (const float*)d_in[6];
  const float* bls = (const float*)d_in[7];

  int N = in_sizes[0] / 256;
  int E = in_sizes[1] / 2;
  const int* src = ei;
  const int* dst = ei + E;

  int NB = (N + 63) >> 6;      // bins of 64 nodes
  int NSUB = NB * 8;           // 8 replicas per bin

  char* ws = (char*)d_ws;
  size_t o = 0;
  auto alloc = [&](size_t b) { size_t c = o; o = (o + b + 511) & ~(size_t)511; return c; };
  int*   cnt     = (int*)(ws + alloc((size_t)N * 4));
  int*   rowptr  = (int*)(ws + alloc((size_t)N * 4));
  float* dinv    = (float*)(ws + alloc((size_t)N * 4));
  int*   bsum    = (int*)(ws + alloc(512));
  int*   subCnt  = (int*)(ws + alloc((size_t)NSUB * 4));
  int*   subPtr  = (int*)(ws + alloc((size_t)NSUB * 4));
  int*   subCur  = (int*)(ws + alloc((size_t)NSUB * 4));
  int*   col     = (int*)(ws + alloc((size_t)E * 4));
  int2*  binned  = (int2*)(ws + alloc((size_t)E * 8));
  unsigned short* W1Th = (unsigned short*)(ws + alloc(128 * 256 * 2));
  unsigned short* W1Tl = (unsigned short*)(ws + alloc(128 * 256 * 2));
  unsigned short* WcTh = (unsigned short*)(ws + alloc(256 * 128 * 2));
  unsigned short* WcTl = (unsigned short*)(ws + alloc(256 * 128 * 2));
  float*  bcat = (float*)(ws + alloc(256 * 4));
  __half* h0   = (__half*)(ws + alloc((size_t)N * 128 * 2));  // GEMM1 out, later g
  __half* hBuf = (__half*)(ws + alloc((size_t)N * 128 * 2));  // h (relu'd)

  float* outMu = (float*)d_out;
  float* outLs = outMu + (size_t)N * 128;

  int nbScanN = (N + 1023) / 1024;
  int nbScanS = (NSUB + 1023) / 1024;
  int gEdge = (E / 4 + 255) / 256;

  // ---- CSR build (binned) ----
  hipMemsetAsync(subCnt, 0, (size_t)NSUB * 4, stream);
  k_sub_hist<<<gEdge, 256, 0, stream>>>(dst, subCnt, E);
  k_blocksum<<<nbScanS, 256, 0, stream>>>(subCnt, bsum, NSUB);
  k_scan_bsum<<<1, 128, 0, stream>>>(bsum, nbScanS);
  k_scan_final<<<nbScanS, 256, 0, stream>>>(subCnt, bsum, subPtr, subCur, nullptr, NSUB);
  k_sub_scatter<<<gEdge, 256, 0, stream>>>(src, dst, subCur, binned, E);
  k_bin_cnt<<<NB, 256, 0, stream>>>(binned, subPtr, subCnt, cnt, N);
  k_blocksum<<<nbScanN, 256, 0, stream>>>(cnt, bsum, N);
  k_scan_bsum<<<1, 128, 0, stream>>>(bsum, nbScanN);
  k_scan_final<<<nbScanN, 256, 0, stream>>>(cnt, bsum, rowptr, nullptr, dinv, N);
  k_bin_place<<<NB, 256, 0, stream>>>(binned, subPtr, subCnt, rowptr, col, N);

  // ---- weights ----
  k_prep_w<<<(2 * 128 * 256 + 256 + 255) / 256, 256, 0, stream>>>(
      W1, Wmu, Wls, bmu, bls, W1Th, W1Tl, WcTh, WcTl, bcat);

  int gx = (N + 127) / 128;
  // h0 = x @ W1                 [N,128] fp16
  k_gemm_mfma<0, 1><<<dim3(gx, 1), 256, 0, stream>>>(x, W1Th, W1Tl, nullptr, h0, nullptr, N, 256, 0);
  // h = relu(A h0 + b1)         [N,128] fp16
  k_spmm_h<<<(N + 3) / 4, 256, 0, stream>>>(h0, rowptr, cnt, col, dinv, b1, hBuf, N, 1, 1);
  // g = A h                     [N,128] fp16 (reuse h0 buffer)
  k_spmm_h<<<(N + 3) / 4, 256, 0, stream>>>(hBuf, rowptr, cnt, col, dinv, nullptr, h0, N, 0, 0);
  // [mu | ls] = g @ [Wmu|Wls] + [bmu|bls]   one fused dispatch, grid.y=2
  k_gemm_mfma<1, 0><<<dim3(gx, 2), 256, 0, stream>>>(h0, WcTh, WcTl, bcat, outMu, outLs, N, 128, 1);
}

// Round 8
// 339.122 us; speedup vs baseline: 1.3815x; 1.3313x over previous
//
#include <hip/hip_runtime.h>
#include <hip/hip_bf16.h>
#include <hip/hip_fp16.h>

typedef __attribute__((ext_vector_type(8))) short bf16x8;
typedef __attribute__((ext_vector_type(8))) short short8;
typedef __attribute__((ext_vector_type(4))) float f32x4;

__device__ __forceinline__ unsigned short bf16_rne(float f) {
  unsigned u = __builtin_bit_cast(unsigned, f);
  unsigned r = u + 0x7fffu + ((u >> 16) & 1u);
  return (unsigned short)(r >> 16);
}
__device__ __forceinline__ float bf16_to_f32(unsigned short h) {
  return __builtin_bit_cast(float, (unsigned)h << 16);
}

// ================= CSR build: two-pass counting sort by dst-bin =================
// bin = dst >> 7 (128 nodes/bin, NBINS <= 1024 for N <= 131072).
// Each block owns EPB contiguous edges; its output windows (subPtr[bin][blk]) are
// private, so every cache line of `binned` is written by ONE CU sequentially.
// Entry packing: src (<2^17) in bits [0,20), dst&127 in bits [20,27).

#define EPB 16384

__global__ __launch_bounds__(256) void k_lhist(const int* __restrict__ dst, int* __restrict__ histT,
                                               int nE, int nblk, int nbins) {
  __shared__ int c[1024];
  int tid = threadIdx.x;
  for (int i = tid; i < nbins; i += 256) c[i] = 0;
  __syncthreads();
  int blk = blockIdx.x;
  int e0 = blk * EPB;
  int e1 = min(nE, e0 + EPB);
  if (e1 - e0 == EPB) {
#pragma unroll
    for (int it = 0; it < EPB / 1024; ++it) {
      int4 d = *(const int4*)(dst + e0 + it * 1024 + tid * 4);
      atomicAdd(&c[d.x >> 7], 1);
      atomicAdd(&c[d.y >> 7], 1);
      atomicAdd(&c[d.z >> 7], 1);
      atomicAdd(&c[d.w >> 7], 1);
    }
  } else {
    for (int i = e0 + tid; i < e1; i += 256) atomicAdd(&c[dst[i] >> 7], 1);
  }
  __syncthreads();
  for (int i = tid; i < nbins; i += 256) histT[i * nblk + blk] = c[i];
}

__global__ __launch_bounds__(256) void k_lscatter(
    const int* __restrict__ src, const int* __restrict__ dst, const int* __restrict__ subPtr,
    int* __restrict__ binned, int nE, int nblk, int nbins) {
  __shared__ int cur[1024];
  int tid = threadIdx.x;
  int blk = blockIdx.x;
  for (int i = tid; i < nbins; i += 256) cur[i] = subPtr[i * nblk + blk];
  __syncthreads();
  int e0 = blk * EPB;
  int e1 = min(nE, e0 + EPB);
  if (e1 - e0 == EPB) {
#pragma unroll
    for (int it = 0; it < EPB / 1024; ++it) {
      int base = e0 + it * 1024 + tid * 4;
      int4 s = *(const int4*)(src + base);
      int4 d = *(const int4*)(dst + base);
      int p0 = atomicAdd(&cur[d.x >> 7], 1);
      int p1 = atomicAdd(&cur[d.y >> 7], 1);
      int p2 = atomicAdd(&cur[d.z >> 7], 1);
      int p3 = atomicAdd(&cur[d.w >> 7], 1);
      binned[p0] = s.x | ((d.x & 127) << 20);
      binned[p1] = s.y | ((d.y & 127) << 20);
      binned[p2] = s.z | ((d.z & 127) << 20);
      binned[p3] = s.w | ((d.w & 127) << 20);
    }
  } else {
    for (int i = e0 + tid; i < e1; i += 256) {
      int d = dst[i];
      int pos = atomicAdd(&cur[d >> 7], 1);
      binned[pos] = src[i] | ((d & 127) << 20);
    }
  }
}

// per-bin degree count: LDS histogram over the bin's 128 nodes, sequential store.
__global__ __launch_bounds__(256) void k_bin_cnt(
    const int* __restrict__ binned, const int* __restrict__ subPtr,
    int* __restrict__ cnt, int nE, int nblk, int nbins, int n) {
  __shared__ int c128[128];
  int b = blockIdx.x;
  int tid = threadIdx.x;
  if (tid < 128) c128[tid] = 0;
  __syncthreads();
  int s0 = subPtr[b * nblk];
  int s1 = (b + 1 < nbins) ? subPtr[(b + 1) * nblk] : nE;
  for (int i = s0 + tid; i < s1; i += 256)
    atomicAdd(&c128[(binned[i] >> 20) & 127], 1);
  __syncthreads();
  if (tid < 128) {
    int idx = (b << 7) + tid;
    if (idx < n) cnt[idx] = c128[tid];
  }
}

// per-bin placement: LDS cursors from rowptr; col writes land in the bin's dense CSR window.
__global__ __launch_bounds__(256) void k_bin_place(
    const int* __restrict__ binned, const int* __restrict__ subPtr,
    const int* __restrict__ rowptr, int* __restrict__ col, int nE, int nblk, int nbins, int n) {
  __shared__ int cur128[128];
  int b = blockIdx.x;
  int tid = threadIdx.x;
  if (tid < 128) {
    int idx = (b << 7) + tid;
    cur128[tid] = (idx < n) ? rowptr[idx] : 0;
  }
  __syncthreads();
  int s0 = subPtr[b * nblk];
  int s1 = (b + 1 < nbins) ? subPtr[(b + 1) * nblk] : nE;
  for (int i = s0 + tid; i < s1; i += 256) {
    int e = binned[i];
    int pos = atomicAdd(&cur128[(e >> 20) & 127], 1);
    col[pos] = e & 0xFFFFF;
  }
}

// ---- 3-phase exclusive scan of cnt[n] -> out (optional fused dinv) ----

__global__ void k_blocksum(const int* __restrict__ cnt, int* __restrict__ bsum, int n) {
  __shared__ int red[256];
  int tid = threadIdx.x;
  int base = blockIdx.x * 1024 + tid * 4;
  int s = 0;
#pragma unroll
  for (int i = 0; i < 4; i++) { int idx = base + i; if (idx < n) s += cnt[idx]; }
  red[tid] = s;
  __syncthreads();
  for (int off = 128; off > 0; off >>= 1) {
    if (tid < off) red[tid] += red[tid + off];
    __syncthreads();
  }
  if (tid == 0) bsum[blockIdx.x] = red[0];
}

__global__ void k_scan_bsum(int* __restrict__ bsum, int nb) {
  __shared__ int s[128];
  int tid = threadIdx.x;
  int v = (tid < nb) ? bsum[tid] : 0;
  s[tid] = v;
  __syncthreads();
  for (int off = 1; off < 128; off <<= 1) {
    int t = (tid >= off) ? s[tid - off] : 0;
    __syncthreads();
    s[tid] += t;
    __syncthreads();
  }
  if (tid < nb) bsum[tid] = s[tid] - v;  // exclusive
}

__global__ void k_scan_final(const int* __restrict__ cnt, const int* __restrict__ bsum,
                             int* __restrict__ rowptr, float* __restrict__ dinv, int n) {
  __shared__ int tsum[256];
  int tid = threadIdx.x;
  int base = blockIdx.x * 1024 + tid * 4;
  int v[4]; int s = 0;
#pragma unroll
  for (int i = 0; i < 4; i++) { v[i] = (base + i < n) ? cnt[base + i] : 0; s += v[i]; }
  tsum[tid] = s;
  __syncthreads();
  for (int off = 1; off < 256; off <<= 1) {
    int t = (tid >= off) ? tsum[tid - off] : 0;
    __syncthreads();
    tsum[tid] += t;
    __syncthreads();
  }
  int run = bsum[blockIdx.x] + tsum[tid] - s;  // exclusive prefix at first elem
#pragma unroll
  for (int i = 0; i < 4; i++) {
    int idx = base + i;
    if (idx < n) {
      rowptr[idx] = run;
      if (dinv) dinv[idx] = rsqrtf((float)(v[i] + 1));  // +1 self-loop
      run += v[i];
    }
  }
}

// ---- weight prep: split-bf16 + transpose; fuse Wmu|Wls, bmu|bls ----

__global__ void k_prep_w(const float* __restrict__ W1,
                         const float* __restrict__ Wmu, const float* __restrict__ Wls,
                         const float* __restrict__ bmu, const float* __restrict__ bls,
                         unsigned short* __restrict__ W1Th, unsigned short* __restrict__ W1Tl,
                         unsigned short* __restrict__ WcTh, unsigned short* __restrict__ WcTl,
                         float* __restrict__ bcat) {
  int i = blockIdx.x * blockDim.x + threadIdx.x;
  if (i < 128 * 256) {                     // W1T [n][k]
    int n = i >> 8, k = i & 255;
    float f = W1[k * 128 + n];
    unsigned short hi = bf16_rne(f);
    W1Th[i] = hi;
    W1Tl[i] = bf16_rne(f - bf16_to_f32(hi));
  } else if (i < 2 * 128 * 256) {          // WcatT [n][k]
    int j = i - 128 * 256;
    int n = j >> 7, k = j & 127;
    float f = (n < 128) ? Wmu[k * 128 + n] : Wls[k * 128 + (n - 128)];
    unsigned short hi = bf16_rne(f);
    WcTh[j] = hi;
    WcTl[j] = bf16_rne(f - bf16_to_f32(hi));
  } else if (i < 2 * 128 * 256 + 256) {    // bcat
    int n = i - 2 * 128 * 256;
    bcat[n] = (n < 128) ? bmu[n] : bls[n - 128];
  }
}

// ---------------- MFMA GEMM ----------------
// Split-precision: A = Ah+Al (bf16), W pre-split WTh/WTl transposed [N][K].
// acc = Ah*Wh + Ah*Wl + Al*Wh. AFMT: 0=f32 A, 1=fp16 A. OFMT: 0=f32 out, 1=fp16 out.

#define LP 40  // LDS row stride in bf16 elems

template <int AFMT, int OFMT>
__global__ __launch_bounds__(256) void k_gemm_mfma(
    const void* __restrict__ Av,
    const unsigned short* __restrict__ WTh, const unsigned short* __restrict__ WTl,
    const float* __restrict__ bias, void* __restrict__ out0, void* __restrict__ out1,
    int M, int K, int split_out) {
  __shared__ unsigned short Ah[128 * LP];
  __shared__ unsigned short Al[128 * LP];
  __shared__ unsigned short Bh[128 * LP];
  __shared__ unsigned short Bl[128 * LP];

  const int tid = threadIdx.x;
  const int lane = tid & 63;
  const int wv = tid >> 6;
  const int wr = wv >> 1, wc = wv & 1;   // 2x2 waves, each 64x64
  const int rsel = lane >> 4;            // 0..3
  const int rrow = lane & 15;
  const int row0 = blockIdx.x * 128;
  const int col0 = blockIdx.y * 128;

  f32x4 acc[4][4];
#pragma unroll
  for (int m = 0; m < 4; m++)
#pragma unroll
    for (int n = 0; n < 4; n++) acc[m][n] = (f32x4){0.f, 0.f, 0.f, 0.f};

  const int srow = tid >> 1;            // staging row 0..127
  const int skh = (tid & 1) * 16;       // k-half 0 or 16

  for (int k0 = 0; k0 < K; k0 += 32) {
    // ---- stage A tile -> split bf16 ----
    if (row0 + srow < M) {
      float fv[16];
      if (AFMT == 0) {
        const float* src = (const float*)Av + (size_t)(row0 + srow) * K + k0 + skh;
        float4 f0 = *(const float4*)(src);
        float4 f1 = *(const float4*)(src + 4);
        float4 f2 = *(const float4*)(src + 8);
        float4 f3 = *(const float4*)(src + 12);
        fv[0]=f0.x; fv[1]=f0.y; fv[2]=f0.z; fv[3]=f0.w;
        fv[4]=f1.x; fv[5]=f1.y; fv[6]=f1.z; fv[7]=f1.w;
        fv[8]=f2.x; fv[9]=f2.y; fv[10]=f2.z; fv[11]=f2.w;
        fv[12]=f3.x; fv[13]=f3.y; fv[14]=f3.z; fv[15]=f3.w;
      } else {
        const __half* src = (const __half*)Av + (size_t)(row0 + srow) * K + k0 + skh;
        short8 r0 = *(const short8*)(src);
        short8 r1 = *(const short8*)(src + 8);
#pragma unroll
        for (int j = 0; j < 8; j++) {
          fv[j]     = __half2float(__builtin_bit_cast(__half, (unsigned short)r0[j]));
          fv[8 + j] = __half2float(__builtin_bit_cast(__half, (unsigned short)r1[j]));
        }
      }
      bf16x8 vh0, vl0, vh1, vl1;
#pragma unroll
      for (int j = 0; j < 8; j++) {
        unsigned short hi = bf16_rne(fv[j]);
        vh0[j] = (short)hi;
        vl0[j] = (short)bf16_rne(fv[j] - bf16_to_f32(hi));
        unsigned short hi2 = bf16_rne(fv[8 + j]);
        vh1[j] = (short)hi2;
        vl1[j] = (short)bf16_rne(fv[8 + j] - bf16_to_f32(hi2));
      }
      *(bf16x8*)&Ah[srow * LP + skh]     = vh0;
      *(bf16x8*)&Ah[srow * LP + skh + 8] = vh1;
      *(bf16x8*)&Al[srow * LP + skh]     = vl0;
      *(bf16x8*)&Al[srow * LP + skh + 8] = vl1;
    } else {
      bf16x8 z = (bf16x8){0,0,0,0,0,0,0,0};
      *(bf16x8*)&Ah[srow * LP + skh] = z; *(bf16x8*)&Ah[srow * LP + skh + 8] = z;
      *(bf16x8*)&Al[srow * LP + skh] = z; *(bf16x8*)&Al[srow * LP + skh + 8] = z;
    }
    // ---- stage W tile ----
    {
      const unsigned short* sh = WTh + (size_t)(col0 + srow) * K + k0 + skh;
      const unsigned short* sl = WTl + (size_t)(col0 + srow) * K + k0 + skh;
      *(bf16x8*)&Bh[srow * LP + skh]     = *(const bf16x8*)sh;
      *(bf16x8*)&Bh[srow * LP + skh + 8] = *(const bf16x8*)(sh + 8);
      *(bf16x8*)&Bl[srow * LP + skh]     = *(const bf16x8*)sl;
      *(bf16x8*)&Bl[srow * LP + skh + 8] = *(const bf16x8*)(sl + 8);
    }
    __syncthreads();

    bf16x8 fah[4], fal[4], fbh[4], fbl[4];
#pragma unroll
    for (int m = 0; m < 4; m++) {
      int off = (wr * 64 + m * 16 + rrow) * LP + rsel * 8;
      fah[m] = *(bf16x8*)&Ah[off];
      fal[m] = *(bf16x8*)&Al[off];
    }
#pragma unroll
    for (int n = 0; n < 4; n++) {
      int off = (wc * 64 + n * 16 + rrow) * LP + rsel * 8;
      fbh[n] = *(bf16x8*)&Bh[off];
      fbl[n] = *(bf16x8*)&Bl[off];
    }
#pragma unroll
    for (int m = 0; m < 4; m++)
#pragma unroll
      for (int n = 0; n < 4; n++) {
        acc[m][n] = __builtin_amdgcn_mfma_f32_16x16x32_bf16(fah[m], fbh[n], acc[m][n], 0, 0, 0);
        acc[m][n] = __builtin_amdgcn_mfma_f32_16x16x32_bf16(fah[m], fbl[n], acc[m][n], 0, 0, 0);
        acc[m][n] = __builtin_amdgcn_mfma_f32_16x16x32_bf16(fal[m], fbh[n], acc[m][n], 0, 0, 0);
      }
    __syncthreads();
  }

  // ---- epilogue: D col=lane&15, row=4*(lane>>4)+reg ----
#pragma unroll
  for (int n = 0; n < 4; n++) {
    int col = col0 + wc * 64 + n * 16 + rrow;
    float badd = bias ? bias[col] : 0.f;
    void* dstBase = out0;
    int c = col;
    if (split_out && c >= 128) { dstBase = out1; c -= 128; }
#pragma unroll
    for (int m = 0; m < 4; m++) {
      f32x4 v = acc[m][n];
#pragma unroll
      for (int r = 0; r < 4; r++) {
        int row = row0 + wr * 64 + m * 16 + rsel * 4 + r;
        if (row < M) {
          if (OFMT == 0)
            ((float*)dstBase)[(size_t)row * 128 + c] = v[r] + badd;
          else
            ((__half*)dstBase)[(size_t)row * 128 + c] = __float2half(v[r] + badd);
        }
      }
    }
  }
}

// ---------------- pull-based SpMM (fp16 rows, on-the-fly norm) ----------------
// out[node] = relu?( dinv[node] * ( dinv[node]*in[node] + sum_e dinv[col]*in[col] ) + bias )

__global__ __launch_bounds__(256) void k_spmm_h(
    const __half* __restrict__ in, const int* __restrict__ rowptr,
    const int* __restrict__ cnt, const int* __restrict__ col,
    const float* __restrict__ dinv,
    const float* __restrict__ bias, __half* __restrict__ out,
    int n, int use_bias, int relu_out) {
  int node = blockIdx.x * 4 + (threadIdx.x >> 6);
  if (node >= n) return;
  int lane = threadIdx.x & 63;

  float di = dinv[node];
  float2 v = __half22float2(((const __half2*)(in + (size_t)node * 128))[lane]);
  float accx = di * v.x;
  float accy = di * v.y;

  int beg = rowptr[node];
  int m = cnt[node];
  int i = 0;
  for (; i + 4 <= m; i += 4) {
    int c0 = col[beg + i], c1 = col[beg + i + 1], c2 = col[beg + i + 2], c3 = col[beg + i + 3];
    float e0 = dinv[c0], e1 = dinv[c1], e2 = dinv[c2], e3 = dinv[c3];
    float2 u0 = __half22float2(((const __half2*)(in + (size_t)c0 * 128))[lane]);
    float2 u1 = __half22float2(((const __half2*)(in + (size_t)c1 * 128))[lane]);
    float2 u2 = __half22float2(((const __half2*)(in + (size_t)c2 * 128))[lane]);
    float2 u3 = __half22float2(((const __half2*)(in + (size_t)c3 * 128))[lane]);
    accx += e0 * u0.x + e1 * u1.x + e2 * u2.x + e3 * u3.x;
    accy += e0 * u0.y + e1 * u1.y + e2 * u2.y + e3 * u3.y;
  }
  for (; i < m; i++) {
    int c0 = col[beg + i];
    float e0 = dinv[c0];
    float2 u0 = __half22float2(((const __half2*)(in + (size_t)c0 * 128))[lane]);
    accx += e0 * u0.x;
    accy += e0 * u0.y;
  }
  accx *= di;
  accy *= di;
  if (use_bias) {
    accx += bias[2 * lane];
    accy += bias[2 * lane + 1];
  }
  if (relu_out) {
    accx = fmaxf(accx, 0.f);
    accy = fmaxf(accy, 0.f);
  }
  ((__half2*)(out + (size_t)node * 128))[lane] = __floats2half2_rn(accx, accy);
}

// ---------------- launch ----------------

extern "C" void kernel_launch(void* const* d_in, const int* in_sizes, int n_in,
                              void* d_out, int out_size, void* d_ws, size_t ws_size,
                              hipStream_t stream) {
  const float* x   = (const float*)d_in[0];
  const int*   ei  = (const int*)d_in[1];
  const float* W1  = (const float*)d_in[2];
  const float* b1  = (const float*)d_in[3];
  const float* Wmu = (const float*)d_in[4];
  const float* bmu = (const float*)d_in[5];
  const float* Wls = (const float*)d_in[6];
  const float* bls = (const float*)d_in[7];

  int N = in_sizes[0] / 256;
  int E = in_sizes[1] / 2;
  const int* src = ei;
  const int* dst = ei + E;

  int NBINS = (N + 127) >> 7;          // 128 nodes per bin (<=1024 for N<=131072)
  int NBLK  = (E + EPB - 1) / EPB;     // edge chunks (blocks)
  int NS    = NBINS * NBLK;            // hist matrix size

  char* ws = (char*)d_ws;
  size_t o = 0;
  auto alloc = [&](size_t b) { size_t c = o; o = (o + b + 511) & ~(size_t)511; return c; };
  int*   cnt     = (int*)(ws + alloc((size_t)N * 4));
  int*   rowptr  = (int*)(ws + alloc((size_t)N * 4));
  float* dinv    = (float*)(ws + alloc((size_t)N * 4));
  int*   bsum    = (int*)(ws + alloc(512));
  int*   histT   = (int*)(ws + alloc((size_t)NS * 4));
  int*   subPtr  = (int*)(ws + alloc((size_t)NS * 4));
  int*   col     = (int*)(ws + alloc((size_t)E * 4));
  int*   binned  = (int*)(ws + alloc((size_t)E * 4));
  unsigned short* W1Th = (unsigned short*)(ws + alloc(128 * 256 * 2));
  unsigned short* W1Tl = (unsigned short*)(ws + alloc(128 * 256 * 2));
  unsigned short* WcTh = (unsigned short*)(ws + alloc(256 * 128 * 2));
  unsigned short* WcTl = (unsigned short*)(ws + alloc(256 * 128 * 2));
  float*  bcat = (float*)(ws + alloc(256 * 4));
  __half* h0   = (__half*)(ws + alloc((size_t)N * 128 * 2));  // GEMM1 out, later g
  __half* hBuf = (__half*)(ws + alloc((size_t)N * 128 * 2));  // h (relu'd)

  float* outMu = (float*)d_out;
  float* outLs = outMu + (size_t)N * 128;

  int nbScanN = (N + 1023) / 1024;
  int nbScanS = (NS + 1023) / 1024;

  // ---- CSR build (counting sort by bin, block-private windows) ----
  k_lhist<<<NBLK, 256, 0, stream>>>(dst, histT, E, NBLK, NBINS);
  k_blocksum<<<nbScanS, 256, 0, stream>>>(histT, bsum, NS);
  k_scan_bsum<<<1, 128, 0, stream>>>(bsum, nbScanS);
  k_scan_final<<<nbScanS, 256, 0, stream>>>(histT, bsum, subPtr, nullptr, NS);
  k_lscatter<<<NBLK, 256, 0, stream>>>(src, dst, subPtr, binned, E, NBLK, NBINS);
  k_bin_cnt<<<NBINS, 256, 0, stream>>>(binned, subPtr, cnt, E, NBLK, NBINS, N);
  k_blocksum<<<nbScanN, 256, 0, stream>>>(cnt, bsum, N);
  k_scan_bsum<<<1, 128, 0, stream>>>(bsum, nbScanN);
  k_scan_final<<<nbScanN, 256, 0, stream>>>(cnt, bsum, rowptr, dinv, N);
  k_bin_place<<<NBINS, 256, 0, stream>>>(binned, subPtr, rowptr, col, E, NBLK, NBINS, N);

  // ---- weights ----
  k_prep_w<<<(2 * 128 * 256 + 256 + 255) / 256, 256, 0, stream>>>(
      W1, Wmu, Wls, bmu, bls, W1Th, W1Tl, WcTh, WcTl, bcat);

  int gx = (N + 127) / 128;
  // h0 = x @ W1                 [N,128] fp16
  k_gemm_mfma<0, 1><<<dim3(gx, 1), 256, 0, stream>>>(x, W1Th, W1Tl, nullptr, h0, nullptr, N, 256, 0);
  // h = relu(A h0 + b1)         [N,128] fp16
  k_spmm_h<<<(N + 3) / 4, 256, 0, stream>>>(h0, rowptr, cnt, col, dinv, b1, hBuf, N, 1, 1);
  // g = A h                     [N,128] fp16 (reuse h0 buffer)
  k_spmm_h<<<(N + 3) / 4, 256, 0, stream>>>(hBuf, rowptr, cnt, col, dinv, nullptr, h0, N, 0, 0);
  // [mu | ls] = g @ [Wmu|Wls] + [bmu|bls]   one fused dispatch, grid.y=2
  k_gemm_mfma<1, 0><<<dim3(gx, 2), 256, 0, stream>>>(h0, WcTh, WcTl, bcat, outMu, outLs, N, 128, 1);
}

// Round 9
// 320.790 us; speedup vs baseline: 1.4604x; 1.0571x over previous
//
#include <hip/hip_runtime.h>
#include <hip/hip_bf16.h>
#include <hip/hip_fp16.h>

typedef __attribute__((ext_vector_type(8))) short bf16x8;
typedef __attribute__((ext_vector_type(8))) short short8;
typedef __attribute__((ext_vector_type(4))) float f32x4;

__device__ __forceinline__ unsigned short bf16_rne(float f) {
  unsigned u = __builtin_bit_cast(unsigned, f);
  unsigned r = u + 0x7fffu + ((u >> 16) & 1u);
  return (unsigned short)(r >> 16);
}
__device__ __forceinline__ float bf16_to_f32(unsigned short h) {
  return __builtin_bit_cast(float, (unsigned)h << 16);
}

// ================= CSR build: two-pass counting sort by dst-bin =================
// bin = dst >> 7 (128 nodes/bin). Each block owns EPB contiguous edges; its output
// windows (subPtr[bin][blk]) are private -> every line of `binned` written by ONE CU.
// Entry packing: src in bits [0,20), dst&127 in bits [20,27).

#define EPB 16384

__global__ __launch_bounds__(256) void k_lhist(const int* __restrict__ dst, int* __restrict__ histT,
                                               int nE, int nblk, int nbins) {
  __shared__ int c[1024];
  int tid = threadIdx.x;
  for (int i = tid; i < nbins; i += 256) c[i] = 0;
  __syncthreads();
  int blk = blockIdx.x;
  int e0 = blk * EPB;
  int e1 = min(nE, e0 + EPB);
  if (e1 - e0 == EPB) {
#pragma unroll
    for (int it = 0; it < EPB / 1024; ++it) {
      int4 d = *(const int4*)(dst + e0 + it * 1024 + tid * 4);
      atomicAdd(&c[d.x >> 7], 1);
      atomicAdd(&c[d.y >> 7], 1);
      atomicAdd(&c[d.z >> 7], 1);
      atomicAdd(&c[d.w >> 7], 1);
    }
  } else {
    for (int i = e0 + tid; i < e1; i += 256) atomicAdd(&c[dst[i] >> 7], 1);
  }
  __syncthreads();
  for (int i = tid; i < nbins; i += 256) histT[i * nblk + blk] = c[i];
}

__global__ __launch_bounds__(256) void k_lscatter(
    const int* __restrict__ src, const int* __restrict__ dst, const int* __restrict__ subPtr,
    int* __restrict__ binned, int nE, int nblk, int nbins) {
  __shared__ int cur[1024];
  int tid = threadIdx.x;
  int blk = blockIdx.x;
  for (int i = tid; i < nbins; i += 256) cur[i] = subPtr[i * nblk + blk];
  __syncthreads();
  int e0 = blk * EPB;
  int e1 = min(nE, e0 + EPB);
  if (e1 - e0 == EPB) {
#pragma unroll
    for (int it = 0; it < EPB / 1024; ++it) {
      int base = e0 + it * 1024 + tid * 4;
      int4 s = *(const int4*)(src + base);
      int4 d = *(const int4*)(dst + base);
      int p0 = atomicAdd(&cur[d.x >> 7], 1);
      int p1 = atomicAdd(&cur[d.y >> 7], 1);
      int p2 = atomicAdd(&cur[d.z >> 7], 1);
      int p3 = atomicAdd(&cur[d.w >> 7], 1);
      binned[p0] = s.x | ((d.x & 127) << 20);
      binned[p1] = s.y | ((d.y & 127) << 20);
      binned[p2] = s.z | ((d.z & 127) << 20);
      binned[p3] = s.w | ((d.w & 127) << 20);
    }
  } else {
    for (int i = e0 + tid; i < e1; i += 256) {
      int d = dst[i];
      int pos = atomicAdd(&cur[d >> 7], 1);
      binned[pos] = src[i] | ((d & 127) << 20);
    }
  }
}

// per-bin degree count: LDS histogram over the bin's 128 nodes, sequential store.
__global__ __launch_bounds__(256) void k_bin_cnt(
    const int* __restrict__ binned, const int* __restrict__ subPtr,
    int* __restrict__ cnt, int nE, int nblk, int nbins, int n) {
  __shared__ int c128[128];
  int b = blockIdx.x;
  int tid = threadIdx.x;
  if (tid < 128) c128[tid] = 0;
  __syncthreads();
  int s0 = subPtr[b * nblk];
  int s1 = (b + 1 < nbins) ? subPtr[(b + 1) * nblk] : nE;
  for (int i = s0 + tid; i < s1; i += 256)
    atomicAdd(&c128[(binned[i] >> 20) & 127], 1);
  __syncthreads();
  if (tid < 128) {
    int idx = (b << 7) + tid;
    if (idx < n) cnt[idx] = c128[tid];
  }
}

// per-bin placement: LDS cursors from rowptr; col writes land in the bin's dense CSR window.
__global__ __launch_bounds__(256) void k_bin_place(
    const int* __restrict__ binned, const int* __restrict__ subPtr,
    const int* __restrict__ rowptr, int* __restrict__ col, int nE, int nblk, int nbins, int n) {
  __shared__ int cur128[128];
  int b = blockIdx.x;
  int tid = threadIdx.x;
  if (tid < 128) {
    int idx = (b << 7) + tid;
    cur128[tid] = (idx < n) ? rowptr[idx] : 0;
  }
  __syncthreads();
  int s0 = subPtr[b * nblk];
  int s1 = (b + 1 < nbins) ? subPtr[(b + 1) * nblk] : nE;
  for (int i = s0 + tid; i < s1; i += 256) {
    int e = binned[i];
    int pos = atomicAdd(&cur128[(e >> 20) & 127], 1);
    col[pos] = e & 0xFFFFF;
  }
}

// ---- 3-phase exclusive scan of cnt[n] -> out (optional fused dinv) ----

__global__ void k_blocksum(const int* __restrict__ cnt, int* __restrict__ bsum, int n) {
  __shared__ int red[256];
  int tid = threadIdx.x;
  int base = blockIdx.x * 1024 + tid * 4;
  int s = 0;
#pragma unroll
  for (int i = 0; i < 4; i++) { int idx = base + i; if (idx < n) s += cnt[idx]; }
  red[tid] = s;
  __syncthreads();
  for (int off = 128; off > 0; off >>= 1) {
    if (tid < off) red[tid] += red[tid + off];
    __syncthreads();
  }
  if (tid == 0) bsum[blockIdx.x] = red[0];
}

__global__ void k_scan_bsum(int* __restrict__ bsum, int nb) {
  __shared__ int s[128];
  int tid = threadIdx.x;
  int v = (tid < nb) ? bsum[tid] : 0;
  s[tid] = v;
  __syncthreads();
  for (int off = 1; off < 128; off <<= 1) {
    int t = (tid >= off) ? s[tid - off] : 0;
    __syncthreads();
    s[tid] += t;
    __syncthreads();
  }
  if (tid < nb) bsum[tid] = s[tid] - v;  // exclusive
}

__global__ void k_scan_final(const int* __restrict__ cnt, const int* __restrict__ bsum,
                             int* __restrict__ rowptr, float* __restrict__ dinv, int n) {
  __shared__ int tsum[256];
  int tid = threadIdx.x;
  int base = blockIdx.x * 1024 + tid * 4;
  int v[4]; int s = 0;
#pragma unroll
  for (int i = 0; i < 4; i++) { v[i] = (base + i < n) ? cnt[base + i] : 0; s += v[i]; }
  tsum[tid] = s;
  __syncthreads();
  for (int off = 1; off < 256; off <<= 1) {
    int t = (tid >= off) ? tsum[tid - off] : 0;
    __syncthreads();
    tsum[tid] += t;
    __syncthreads();
  }
  int run = bsum[blockIdx.x] + tsum[tid] - s;  // exclusive prefix at first elem
#pragma unroll
  for (int i = 0; i < 4; i++) {
    int idx = base + i;
    if (idx < n) {
      rowptr[idx] = run;
      if (dinv) dinv[idx] = rsqrtf((float)(v[i] + 1));  // +1 self-loop
      run += v[i];
    }
  }
}

// ---- weight prep: split-bf16 + transpose; fuse Wmu|Wls, bmu|bls ----

__global__ void k_prep_w(const float* __restrict__ W1,
                         const float* __restrict__ Wmu, const float* __restrict__ Wls,
                         const float* __restrict__ bmu, const float* __restrict__ bls,
                         unsigned short* __restrict__ W1Th, unsigned short* __restrict__ W1Tl,
                         unsigned short* __restrict__ WcTh, unsigned short* __restrict__ WcTl,
                         float* __restrict__ bcat) {
  int i = blockIdx.x * blockDim.x + threadIdx.x;
  if (i < 128 * 256) {                     // W1T [n][k]
    int n = i >> 8, k = i & 255;
    float f = W1[k * 128 + n];
    unsigned short hi = bf16_rne(f);
    W1Th[i] = hi;
    W1Tl[i] = bf16_rne(f - bf16_to_f32(hi));
  } else if (i < 2 * 128 * 256) {          // WcatT [n][k]
    int j = i - 128 * 256;
    int n = j >> 7, k = j & 127;
    float f = (n < 128) ? Wmu[k * 128 + n] : Wls[k * 128 + (n - 128)];
    unsigned short hi = bf16_rne(f);
    WcTh[j] = hi;
    WcTl[j] = bf16_rne(f - bf16_to_f32(hi));
  } else if (i < 2 * 128 * 256 + 256) {    // bcat
    int n = i - 2 * 128 * 256;
    bcat[n] = (n < 128) ? bmu[n] : bls[n - 128];
  }
}

// ---------------- MFMA GEMM ----------------
// Split-precision: A = Ah+Al (bf16), W pre-split WTh/WTl transposed [N][K].
// acc = Ah*Wh + Ah*Wl + Al*Wh. AFMT: 0=f32 A, 1=fp16 A. OFMT: 0=f32 out, 1=fp16 out.

#define LP 40  // LDS row stride in bf16 elems

template <int AFMT, int OFMT>
__global__ __launch_bounds__(256) void k_gemm_mfma(
    const void* __restrict__ Av,
    const unsigned short* __restrict__ WTh, const unsigned short* __restrict__ WTl,
    const float* __restrict__ bias, void* __restrict__ out0, void* __restrict__ out1,
    int M, int K, int split_out) {
  __shared__ unsigned short Ah[128 * LP];
  __shared__ unsigned short Al[128 * LP];
  __shared__ unsigned short Bh[128 * LP];
  __shared__ unsigned short Bl[128 * LP];

  const int tid = threadIdx.x;
  const int lane = tid & 63;
  const int wv = tid >> 6;
  const int wr = wv >> 1, wc = wv & 1;   // 2x2 waves, each 64x64
  const int rsel = lane >> 4;            // 0..3
  const int rrow = lane & 15;
  const int row0 = blockIdx.x * 128;
  const int col0 = blockIdx.y * 128;

  f32x4 acc[4][4];
#pragma unroll
  for (int m = 0; m < 4; m++)
#pragma unroll
    for (int n = 0; n < 4; n++) acc[m][n] = (f32x4){0.f, 0.f, 0.f, 0.f};

  const int srow = tid >> 1;            // staging row 0..127
  const int skh = (tid & 1) * 16;       // k-half 0 or 16

  for (int k0 = 0; k0 < K; k0 += 32) {
    // ---- stage A tile -> split bf16 ----
    if (row0 + srow < M) {
      float fv[16];
      if (AFMT == 0) {
        const float* src = (const float*)Av + (size_t)(row0 + srow) * K + k0 + skh;
        float4 f0 = *(const float4*)(src);
        float4 f1 = *(const float4*)(src + 4);
        float4 f2 = *(const float4*)(src + 8);
        float4 f3 = *(const float4*)(src + 12);
        fv[0]=f0.x; fv[1]=f0.y; fv[2]=f0.z; fv[3]=f0.w;
        fv[4]=f1.x; fv[5]=f1.y; fv[6]=f1.z; fv[7]=f1.w;
        fv[8]=f2.x; fv[9]=f2.y; fv[10]=f2.z; fv[11]=f2.w;
        fv[12]=f3.x; fv[13]=f3.y; fv[14]=f3.z; fv[15]=f3.w;
      } else {
        const __half* src = (const __half*)Av + (size_t)(row0 + srow) * K + k0 + skh;
        short8 r0 = *(const short8*)(src);
        short8 r1 = *(const short8*)(src + 8);
#pragma unroll
        for (int j = 0; j < 8; j++) {
          fv[j]     = __half2float(__builtin_bit_cast(__half, (unsigned short)r0[j]));
          fv[8 + j] = __half2float(__builtin_bit_cast(__half, (unsigned short)r1[j]));
        }
      }
      bf16x8 vh0, vl0, vh1, vl1;
#pragma unroll
      for (int j = 0; j < 8; j++) {
        unsigned short hi = bf16_rne(fv[j]);
        vh0[j] = (short)hi;
        vl0[j] = (short)bf16_rne(fv[j] - bf16_to_f32(hi));
        unsigned short hi2 = bf16_rne(fv[8 + j]);
        vh1[j] = (short)hi2;
        vl1[j] = (short)bf16_rne(fv[8 + j] - bf16_to_f32(hi2));
      }
      *(bf16x8*)&Ah[srow * LP + skh]     = vh0;
      *(bf16x8*)&Ah[srow * LP + skh + 8] = vh1;
      *(bf16x8*)&Al[srow * LP + skh]     = vl0;
      *(bf16x8*)&Al[srow * LP + skh + 8] = vl1;
    } else {
      bf16x8 z = (bf16x8){0,0,0,0,0,0,0,0};
      *(bf16x8*)&Ah[srow * LP + skh] = z; *(bf16x8*)&Ah[srow * LP + skh + 8] = z;
      *(bf16x8*)&Al[srow * LP + skh] = z; *(bf16x8*)&Al[srow * LP + skh + 8] = z;
    }
    // ---- stage W tile ----
    {
      const unsigned short* sh = WTh + (size_t)(col0 + srow) * K + k0 + skh;
      const unsigned short* sl = WTl + (size_t)(col0 + srow) * K + k0 + skh;
      *(bf16x8*)&Bh[srow * LP + skh]     = *(const bf16x8*)sh;
      *(bf16x8*)&Bh[srow * LP + skh + 8] = *(const bf16x8*)(sh + 8);
      *(bf16x8*)&Bl[srow * LP + skh]     = *(const bf16x8*)sl;
      *(bf16x8*)&Bl[srow * LP + skh + 8] = *(const bf16x8*)(sl + 8);
    }
    __syncthreads();

    bf16x8 fah[4], fal[4], fbh[4], fbl[4];
#pragma unroll
    for (int m = 0; m < 4; m++) {
      int off = (wr * 64 + m * 16 + rrow) * LP + rsel * 8;
      fah[m] = *(bf16x8*)&Ah[off];
      fal[m] = *(bf16x8*)&Al[off];
    }
#pragma unroll
    for (int n = 0; n < 4; n++) {
      int off = (wc * 64 + n * 16 + rrow) * LP + rsel * 8;
      fbh[n] = *(bf16x8*)&Bh[off];
      fbl[n] = *(bf16x8*)&Bl[off];
    }
#pragma unroll
    for (int m = 0; m < 4; m++)
#pragma unroll
      for (int n = 0; n < 4; n++) {
        acc[m][n] = __builtin_amdgcn_mfma_f32_16x16x32_bf16(fah[m], fbh[n], acc[m][n], 0, 0, 0);
        acc[m][n] = __builtin_amdgcn_mfma_f32_16x16x32_bf16(fah[m], fbl[n], acc[m][n], 0, 0, 0);
        acc[m][n] = __builtin_amdgcn_mfma_f32_16x16x32_bf16(fal[m], fbh[n], acc[m][n], 0, 0, 0);
      }
    __syncthreads();
  }

  // ---- epilogue: D col=lane&15, row=4*(lane>>4)+reg ----
#pragma unroll
  for (int n = 0; n < 4; n++) {
    int col = col0 + wc * 64 + n * 16 + rrow;
    float badd = bias ? bias[col] : 0.f;
    void* dstBase = out0;
    int c = col;
    if (split_out && c >= 128) { dstBase = out1; c -= 128; }
#pragma unroll
    for (int m = 0; m < 4; m++) {
      f32x4 v = acc[m][n];
#pragma unroll
      for (int r = 0; r < 4; r++) {
        int row = row0 + wr * 64 + m * 16 + rsel * 4 + r;
        if (row < M) {
          if (OFMT == 0)
            ((float*)dstBase)[(size_t)row * 128 + c] = v[r] + badd;
          else
            ((__half*)dstBase)[(size_t)row * 128 + c] = __float2half(v[r] + badd);
        }
      }
    }
  }
}

// ---------------- pull-based SpMM (fp16 rows, on-the-fly norm) ----------------
// out[node] = relu?( dinv[node] * ( dinv[node]*in[node] + sum_e dinv[col]*in[col] ) + bias )
// Unroll-8 with masked batched tail: max MLP, no serialized remainder chain.

__global__ __launch_bounds__(256) void k_spmm_h(
    const __half* __restrict__ in, const int* __restrict__ rowptr,
    const int* __restrict__ cnt, const int* __restrict__ col,
    const float* __restrict__ dinv,
    const float* __restrict__ bias, __half* __restrict__ out,
    int n, int use_bias, int relu_out) {
  int node = blockIdx.x * 4 + (threadIdx.x >> 6);
  if (node >= n) return;
  int lane = threadIdx.x & 63;

  const __half2* inp = (const __half2*)in;
  float di = dinv[node];
  float2 v = __half22float2(inp[(size_t)node * 64 + lane]);
  float accx = di * v.x;
  float accy = di * v.y;

  int beg = rowptr[node];
  int m = cnt[node];
  int i = 0;
  for (; i + 8 <= m; i += 8) {
    int c[8];
#pragma unroll
    for (int j = 0; j < 8; j++) c[j] = col[beg + i + j];
    float e[8];
#pragma unroll
    for (int j = 0; j < 8; j++) e[j] = dinv[c[j]];
    float2 u[8];
#pragma unroll
    for (int j = 0; j < 8; j++) u[j] = __half22float2(inp[(size_t)c[j] * 64 + lane]);
#pragma unroll
    for (int j = 0; j < 8; j++) { accx += e[j] * u[j].x; accy += e[j] * u[j].y; }
  }
  if (i < m) {  // masked batch: pad entries re-gather a valid row with weight 0
    int c[8];
#pragma unroll
    for (int j = 0; j < 8; j++) c[j] = col[(i + j < m) ? (beg + i + j) : beg];
    float e[8];
#pragma unroll
    for (int j = 0; j < 8; j++) e[j] = (i + j < m) ? dinv[c[j]] : 0.f;
    float2 u[8];
#pragma unroll
    for (int j = 0; j < 8; j++) u[j] = __half22float2(inp[(size_t)c[j] * 64 + lane]);
#pragma unroll
    for (int j = 0; j < 8; j++) { accx += e[j] * u[j].x; accy += e[j] * u[j].y; }
  }
  accx *= di;
  accy *= di;
  if (use_bias) {
    accx += bias[2 * lane];
    accy += bias[2 * lane + 1];
  }
  if (relu_out) {
    accx = fmaxf(accx, 0.f);
    accy = fmaxf(accy, 0.f);
  }
  ((__half2*)(out + (size_t)node * 128))[lane] = __floats2half2_rn(accx, accy);
}

// ---------------- launch ----------------

extern "C" void kernel_launch(void* const* d_in, const int* in_sizes, int n_in,
                              void* d_out, int out_size, void* d_ws, size_t ws_size,
                              hipStream_t stream) {
  const float* x   = (const float*)d_in[0];
  const int*   ei  = (const int*)d_in[1];
  const float* W1  = (const float*)d_in[2];
  const float* b1  = (const float*)d_in[3];
  const float* Wmu = (const float*)d_in[4];
  const float* bmu = (const float*)d_in[5];
  const float* Wls = (const float*)d_in[6];
  const float* bls = (const float*)d_in[7];

  int N = in_sizes[0] / 256;
  int E = in_sizes[1] / 2;
  const int* src = ei;
  const int* dst = ei + E;

  int NBINS = (N + 127) >> 7;          // 128 nodes per bin
  int NBLK  = (E + EPB - 1) / EPB;     // edge chunks (blocks)
  int NS    = NBINS * NBLK;            // hist matrix size

  char* ws = (char*)d_ws;
  size_t o = 0;
  auto alloc = [&](size_t b) { size_t c = o; o = (o + b + 511) & ~(size_t)511; return c; };
  int*   cnt     = (int*)(ws + alloc((size_t)N * 4));
  int*   rowptr  = (int*)(ws + alloc((size_t)N * 4));
  float* dinv    = (float*)(ws + alloc((size_t)N * 4));
  int*   bsum    = (int*)(ws + alloc(512));
  int*   histT   = (int*)(ws + alloc((size_t)NS * 4));
  int*   subPtr  = (int*)(ws + alloc((size_t)NS * 4));
  int*   col     = (int*)(ws + alloc((size_t)E * 4));
  int*   binned  = (int*)(ws + alloc((size_t)E * 4));
  unsigned short* W1Th = (unsigned short*)(ws + alloc(128 * 256 * 2));
  unsigned short* W1Tl = (unsigned short*)(ws + alloc(128 * 256 * 2));
  unsigned short* WcTh = (unsigned short*)(ws + alloc(256 * 128 * 2));
  unsigned short* WcTl = (unsigned short*)(ws + alloc(256 * 128 * 2));
  float*  bcat = (float*)(ws + alloc(256 * 4));
  __half* h0   = (__half*)(ws + alloc((size_t)N * 128 * 2));  // GEMM1 out, later g
  __half* hBuf = (__half*)(ws + alloc((size_t)N * 128 * 2));  // h (relu'd)

  float* outMu = (float*)d_out;
  float* outLs = outMu + (size_t)N * 128;

  int nbScanN = (N + 1023) / 1024;
  int nbScanS = (NS + 1023) / 1024;

  // ---- CSR build (counting sort by bin, block-private windows) ----
  k_lhist<<<NBLK, 256, 0, stream>>>(dst, histT, E, NBLK, NBINS);
  k_blocksum<<<nbScanS, 256, 0, stream>>>(histT, bsum, NS);
  k_scan_bsum<<<1, 128, 0, stream>>>(bsum, nbScanS);
  k_scan_final<<<nbScanS, 256, 0, stream>>>(histT, bsum, subPtr, nullptr, NS);
  k_lscatter<<<NBLK, 256, 0, stream>>>(src, dst, subPtr, binned, E, NBLK, NBINS);
  k_bin_cnt<<<NBINS, 256, 0, stream>>>(binned, subPtr, cnt, E, NBLK, NBINS, N);
  k_blocksum<<<nbScanN, 256, 0, stream>>>(cnt, bsum, N);
  k_scan_bsum<<<1, 128, 0, stream>>>(bsum, nbScanN);
  k_scan_final<<<nbScanN, 256, 0, stream>>>(cnt, bsum, rowptr, dinv, N);
  k_bin_place<<<NBINS, 256, 0, stream>>>(binned, subPtr, rowptr, col, E, NBLK, NBINS, N);

  // ---- weights ----
  k_prep_w<<<(2 * 128 * 256 + 256 + 255) / 256, 256, 0, stream>>>(
      W1, Wmu, Wls, bmu, bls, W1Th, W1Tl, WcTh, WcTl, bcat);

  int gx = (N + 127) / 128;
  // h0 = x @ W1                 [N,128] fp16
  k_gemm_mfma<0, 1><<<dim3(gx, 1), 256, 0, stream>>>(x, W1Th, W1Tl, nullptr, h0, nullptr, N, 256, 0);
  // h = relu(A h0 + b1)         [N,128] fp16
  k_spmm_h<<<(N + 3) / 4, 256, 0, stream>>>(h0, rowptr, cnt, col, dinv, b1, hBuf, N, 1, 1);
  // g = A h                     [N,128] fp16 (reuse h0 buffer)
  k_spmm_h<<<(N + 3) / 4, 256, 0, stream>>>(hBuf, rowptr, cnt, col, dinv, nullptr, h0, N, 0, 0);
  // [mu | ls] = g @ [Wmu|Wls] + [bmu|bls]   one fused dispatch, grid.y=2
  k_gemm_mfma<1, 0><<<dim3(gx, 2), 256, 0, stream>>>(h0, WcTh, WcTl, bcat, outMu, outLs, N, 128, 1);
}

// Round 10
// 306.946 us; speedup vs baseline: 1.5263x; 1.0451x over previous
//
#include <hip/hip_runtime.h>
#include <hip/hip_bf16.h>
#include <hip/hip_fp16.h>

typedef __attribute__((ext_vector_type(8))) short short8;
typedef __attribute__((ext_vector_type(8))) _Float16 f16x8;
typedef __attribute__((ext_vector_type(4))) float f32x4;

// ================= CSR build: two-pass counting sort by dst-bin =================
// bin = dst >> 7 (128 nodes/bin). Each block owns EPB contiguous edges; its output
// windows (subPtr[bin][blk]) are private -> every line of `binned` written by ONE CU.
// Entry packing: src in bits [0,20), dst&127 in bits [20,27).

#define EPB 16384

__global__ __launch_bounds__(256) void k_lhist(const int* __restrict__ dst, int* __restrict__ histT,
                                               int nE, int nblk, int nbins) {
  __shared__ int c[1024];
  int tid = threadIdx.x;
  for (int i = tid; i < nbins; i += 256) c[i] = 0;
  __syncthreads();
  int blk = blockIdx.x;
  int e0 = blk * EPB;
  int e1 = min(nE, e0 + EPB);
  if (e1 - e0 == EPB) {
#pragma unroll
    for (int it = 0; it < EPB / 1024; ++it) {
      int4 d = *(const int4*)(dst + e0 + it * 1024 + tid * 4);
      atomicAdd(&c[d.x >> 7], 1);
      atomicAdd(&c[d.y >> 7], 1);
      atomicAdd(&c[d.z >> 7], 1);
      atomicAdd(&c[d.w >> 7], 1);
    }
  } else {
    for (int i = e0 + tid; i < e1; i += 256) atomicAdd(&c[dst[i] >> 7], 1);
  }
  __syncthreads();
  for (int i = tid; i < nbins; i += 256) histT[i * nblk + blk] = c[i];
}

__global__ __launch_bounds__(256) void k_lscatter(
    const int* __restrict__ src, const int* __restrict__ dst, const int* __restrict__ subPtr,
    int* __restrict__ binned, int nE, int nblk, int nbins) {
  __shared__ int cur[1024];
  int tid = threadIdx.x;
  int blk = blockIdx.x;
  for (int i = tid; i < nbins; i += 256) cur[i] = subPtr[i * nblk + blk];
  __syncthreads();
  int e0 = blk * EPB;
  int e1 = min(nE, e0 + EPB);
  if (e1 - e0 == EPB) {
#pragma unroll
    for (int it = 0; it < EPB / 1024; ++it) {
      int base = e0 + it * 1024 + tid * 4;
      int4 s = *(const int4*)(src + base);
      int4 d = *(const int4*)(dst + base);
      int p0 = atomicAdd(&cur[d.x >> 7], 1);
      int p1 = atomicAdd(&cur[d.y >> 7], 1);
      int p2 = atomicAdd(&cur[d.z >> 7], 1);
      int p3 = atomicAdd(&cur[d.w >> 7], 1);
      binned[p0] = s.x | ((d.x & 127) << 20);
      binned[p1] = s.y | ((d.y & 127) << 20);
      binned[p2] = s.z | ((d.z & 127) << 20);
      binned[p3] = s.w | ((d.w & 127) << 20);
    }
  } else {
    for (int i = e0 + tid; i < e1; i += 256) {
      int d = dst[i];
      int pos = atomicAdd(&cur[d >> 7], 1);
      binned[pos] = src[i] | ((d & 127) << 20);
    }
  }
}

// per-bin degree count: LDS histogram over the bin's 128 nodes, sequential store.
__global__ __launch_bounds__(256) void k_bin_cnt(
    const int* __restrict__ binned, const int* __restrict__ subPtr,
    int* __restrict__ cnt, int nE, int nblk, int nbins, int n) {
  __shared__ int c128[128];
  int b = blockIdx.x;
  int tid = threadIdx.x;
  if (tid < 128) c128[tid] = 0;
  __syncthreads();
  int s0 = subPtr[b * nblk];
  int s1 = (b + 1 < nbins) ? subPtr[(b + 1) * nblk] : nE;
  for (int i = s0 + tid; i < s1; i += 256)
    atomicAdd(&c128[(binned[i] >> 20) & 127], 1);
  __syncthreads();
  if (tid < 128) {
    int idx = (b << 7) + tid;
    if (idx < n) cnt[idx] = c128[tid];
  }
}

// per-bin placement: LDS cursors from rowptr; col writes land in the bin's dense CSR window.
__global__ __launch_bounds__(256) void k_bin_place(
    const int* __restrict__ binned, const int* __restrict__ subPtr,
    const int* __restrict__ rowptr, int* __restrict__ col, int nE, int nblk, int nbins, int n) {
  __shared__ int cur128[128];
  int b = blockIdx.x;
  int tid = threadIdx.x;
  if (tid < 128) {
    int idx = (b << 7) + tid;
    cur128[tid] = (idx < n) ? rowptr[idx] : 0;
  }
  __syncthreads();
  int s0 = subPtr[b * nblk];
  int s1 = (b + 1 < nbins) ? subPtr[(b + 1) * nblk] : nE;
  for (int i = s0 + tid; i < s1; i += 256) {
    int e = binned[i];
    int pos = atomicAdd(&cur128[(e >> 20) & 127], 1);
    col[pos] = e & 0xFFFFF;
  }
}

// ---- 3-phase exclusive scan of cnt[n] -> out (optional fused dinv) ----

__global__ void k_blocksum(const int* __restrict__ cnt, int* __restrict__ bsum, int n) {
  __shared__ int red[256];
  int tid = threadIdx.x;
  int base = blockIdx.x * 1024 + tid * 4;
  int s = 0;
#pragma unroll
  for (int i = 0; i < 4; i++) { int idx = base + i; if (idx < n) s += cnt[idx]; }
  red[tid] = s;
  __syncthreads();
  for (int off = 128; off > 0; off >>= 1) {
    if (tid < off) red[tid] += red[tid + off];
    __syncthreads();
  }
  if (tid == 0) bsum[blockIdx.x] = red[0];
}

__global__ void k_scan_bsum(int* __restrict__ bsum, int nb) {
  __shared__ int s[128];
  int tid = threadIdx.x;
  int v = (tid < nb) ? bsum[tid] : 0;
  s[tid] = v;
  __syncthreads();
  for (int off = 1; off < 128; off <<= 1) {
    int t = (tid >= off) ? s[tid - off] : 0;
    __syncthreads();
    s[tid] += t;
    __syncthreads();
  }
  if (tid < nb) bsum[tid] = s[tid] - v;  // exclusive
}

__global__ void k_scan_final(const int* __restrict__ cnt, const int* __restrict__ bsum,
                             int* __restrict__ rowptr, float* __restrict__ dinv, int n) {
  __shared__ int tsum[256];
  int tid = threadIdx.x;
  int base = blockIdx.x * 1024 + tid * 4;
  int v[4]; int s = 0;
#pragma unroll
  for (int i = 0; i < 4; i++) { v[i] = (base + i < n) ? cnt[base + i] : 0; s += v[i]; }
  tsum[tid] = s;
  __syncthreads();
  for (int off = 1; off < 256; off <<= 1) {
    int t = (tid >= off) ? tsum[tid - off] : 0;
    __syncthreads();
    tsum[tid] += t;
    __syncthreads();
  }
  int run = bsum[blockIdx.x] + tsum[tid] - s;  // exclusive prefix at first elem
#pragma unroll
  for (int i = 0; i < 4; i++) {
    int idx = base + i;
    if (idx < n) {
      rowptr[idx] = run;
      if (dinv) dinv[idx] = rsqrtf((float)(v[i] + 1));  // +1 self-loop
      run += v[i];
    }
  }
}

// ---- weight prep: fp16 + transpose; fuse Wmu|Wls, bmu|bls ----

__global__ void k_prep_w(const float* __restrict__ W1,
                         const float* __restrict__ Wmu, const float* __restrict__ Wls,
                         const float* __restrict__ bmu, const float* __restrict__ bls,
                         __half* __restrict__ W1T, __half* __restrict__ WcT,
                         float* __restrict__ bcat) {
  int i = blockIdx.x * blockDim.x + threadIdx.x;
  if (i < 128 * 256) {                     // W1T [n][k]
    int n = i >> 8, k = i & 255;
    W1T[i] = __float2half(W1[k * 128 + n]);
  } else if (i < 2 * 128 * 256) {          // WcT [n][k]
    int j = i - 128 * 256;
    int n = j >> 7, k = j & 127;
    float f = (n < 128) ? Wmu[k * 128 + n] : Wls[k * 128 + (n - 128)];
    WcT[j] = __float2half(f);
  } else if (i < 2 * 128 * 256 + 256) {    // bcat
    int n = i - 2 * 128 * 256;
    bcat[n] = (n < 128) ? bmu[n] : bls[n - 128];
  }
}

// ---------------- MFMA GEMM (fp16 x fp16, single-term) ----------------
// W pre-converted fp16, transposed [N][K]. AFMT: 0=f32 A (cvt in staging), 1=fp16 A (pure copy).
// OFMT: 0=f32 out (+bias, split), 1=fp16 out.

#define LP 40  // LDS row stride in halves (32 + 8 pad; 80B = 5 x 16B keeps alignment)

template <int AFMT, int OFMT>
__global__ __launch_bounds__(256) void k_gemm_mfma(
    const void* __restrict__ Av, const __half* __restrict__ WT,
    const float* __restrict__ bias, void* __restrict__ out0, void* __restrict__ out1,
    int M, int K, int split_out) {
  __shared__ _Float16 As[128 * LP];
  __shared__ _Float16 Bs[128 * LP];

  const int tid = threadIdx.x;
  const int lane = tid & 63;
  const int wv = tid >> 6;
  const int wr = wv >> 1, wc = wv & 1;   // 2x2 waves, each 64x64
  const int rsel = lane >> 4;            // 0..3
  const int rrow = lane & 15;
  const int row0 = blockIdx.x * 128;
  const int col0 = blockIdx.y * 128;

  f32x4 acc[4][4];
#pragma unroll
  for (int m = 0; m < 4; m++)
#pragma unroll
    for (int n = 0; n < 4; n++) acc[m][n] = (f32x4){0.f, 0.f, 0.f, 0.f};

  const int srow = tid >> 1;            // staging row 0..127
  const int skh = (tid & 1) * 16;       // k-half 0 or 16

  for (int k0 = 0; k0 < K; k0 += 32) {
    // ---- stage A tile ----
    if (row0 + srow < M) {
      if (AFMT == 0) {
        const float* src = (const float*)Av + (size_t)(row0 + srow) * K + k0 + skh;
        float4 f0 = *(const float4*)(src);
        float4 f1 = *(const float4*)(src + 4);
        float4 f2 = *(const float4*)(src + 8);
        float4 f3 = *(const float4*)(src + 12);
        f16x8 v0, v1;
        v0[0]=(_Float16)f0.x; v0[1]=(_Float16)f0.y; v0[2]=(_Float16)f0.z; v0[3]=(_Float16)f0.w;
        v0[4]=(_Float16)f1.x; v0[5]=(_Float16)f1.y; v0[6]=(_Float16)f1.z; v0[7]=(_Float16)f1.w;
        v1[0]=(_Float16)f2.x; v1[1]=(_Float16)f2.y; v1[2]=(_Float16)f2.z; v1[3]=(_Float16)f2.w;
        v1[4]=(_Float16)f3.x; v1[5]=(_Float16)f3.y; v1[6]=(_Float16)f3.z; v1[7]=(_Float16)f3.w;
        *(f16x8*)&As[srow * LP + skh]     = v0;
        *(f16x8*)&As[srow * LP + skh + 8] = v1;
      } else {
        const _Float16* src = (const _Float16*)Av + (size_t)(row0 + srow) * K + k0 + skh;
        *(f16x8*)&As[srow * LP + skh]     = *(const f16x8*)src;
        *(f16x8*)&As[srow * LP + skh + 8] = *(const f16x8*)(src + 8);
      }
    } else {
      f16x8 z = (f16x8){0,0,0,0,0,0,0,0};
      *(f16x8*)&As[srow * LP + skh] = z; *(f16x8*)&As[srow * LP + skh + 8] = z;
    }
    // ---- stage W tile (fp16, transposed [N][K]) ----
    {
      const _Float16* s = (const _Float16*)WT + (size_t)(col0 + srow) * K + k0 + skh;
      *(f16x8*)&Bs[srow * LP + skh]     = *(const f16x8*)s;
      *(f16x8*)&Bs[srow * LP + skh + 8] = *(const f16x8*)(s + 8);
    }
    __syncthreads();

    f16x8 fa[4], fb[4];
#pragma unroll
    for (int m = 0; m < 4; m++)
      fa[m] = *(f16x8*)&As[(wr * 64 + m * 16 + rrow) * LP + rsel * 8];
#pragma unroll
    for (int n = 0; n < 4; n++)
      fb[n] = *(f16x8*)&Bs[(wc * 64 + n * 16 + rrow) * LP + rsel * 8];
#pragma unroll
    for (int m = 0; m < 4; m++)
#pragma unroll
      for (int n = 0; n < 4; n++)
        acc[m][n] = __builtin_amdgcn_mfma_f32_16x16x32_f16(fa[m], fb[n], acc[m][n], 0, 0, 0);
    __syncthreads();
  }

  // ---- epilogue: D col=lane&15, row=4*(lane>>4)+reg ----
#pragma unroll
  for (int n = 0; n < 4; n++) {
    int col = col0 + wc * 64 + n * 16 + rrow;
    float badd = bias ? bias[col] : 0.f;
    void* dstBase = out0;
    int c = col;
    if (split_out && c >= 128) { dstBase = out1; c -= 128; }
#pragma unroll
    for (int m = 0; m < 4; m++) {
      f32x4 v = acc[m][n];
#pragma unroll
      for (int r = 0; r < 4; r++) {
        int row = row0 + wr * 64 + m * 16 + rsel * 4 + r;
        if (row < M) {
          if (OFMT == 0)
            ((float*)dstBase)[(size_t)row * 128 + c] = v[r] + badd;
          else
            ((__half*)dstBase)[(size_t)row * 128 + c] = __float2half(v[r] + badd);
        }
      }
    }
  }
}

// ---------------- pull-based SpMM (fp16 rows, on-the-fly norm) ----------------
// out[node] = relu?( dinv[node] * ( dinv[node]*in[node] + sum_e dinv[col]*in[col] ) + bias )
// Unroll-8 with masked batched tail: max MLP, no serialized remainder chain.

__global__ __launch_bounds__(256) void k_spmm_h(
    const __half* __restrict__ in, const int* __restrict__ rowptr,
    const int* __restrict__ cnt, const int* __restrict__ col,
    const float* __restrict__ dinv,
    const float* __restrict__ bias, __half* __restrict__ out,
    int n, int use_bias, int relu_out) {
  int node = blockIdx.x * 4 + (threadIdx.x >> 6);
  if (node >= n) return;
  int lane = threadIdx.x & 63;

  const __half2* inp = (const __half2*)in;
  float di = dinv[node];
  float2 v = __half22float2(inp[(size_t)node * 64 + lane]);
  float accx = di * v.x;
  float accy = di * v.y;

  int beg = rowptr[node];
  int m = cnt[node];
  int i = 0;
  for (; i + 8 <= m; i += 8) {
    int c[8];
#pragma unroll
    for (int j = 0; j < 8; j++) c[j] = col[beg + i + j];
    float e[8];
#pragma unroll
    for (int j = 0; j < 8; j++) e[j] = dinv[c[j]];
    float2 u[8];
#pragma unroll
    for (int j = 0; j < 8; j++) u[j] = __half22float2(inp[(size_t)c[j] * 64 + lane]);
#pragma unroll
    for (int j = 0; j < 8; j++) { accx += e[j] * u[j].x; accy += e[j] * u[j].y; }
  }
  if (i < m) {  // masked batch: pad entries re-gather a valid row with weight 0
    int c[8];
#pragma unroll
    for (int j = 0; j < 8; j++) c[j] = col[(i + j < m) ? (beg + i + j) : beg];
    float e[8];
#pragma unroll
    for (int j = 0; j < 8; j++) e[j] = (i + j < m) ? dinv[c[j]] : 0.f;
    float2 u[8];
#pragma unroll
    for (int j = 0; j < 8; j++) u[j] = __half22float2(inp[(size_t)c[j] * 64 + lane]);
#pragma unroll
    for (int j = 0; j < 8; j++) { accx += e[j] * u[j].x; accy += e[j] * u[j].y; }
  }
  accx *= di;
  accy *= di;
  if (use_bias) {
    accx += bias[2 * lane];
    accy += bias[2 * lane + 1];
  }
  if (relu_out) {
    accx = fmaxf(accx, 0.f);
    accy = fmaxf(accy, 0.f);
  }
  ((__half2*)(out + (size_t)node * 128))[lane] = __floats2half2_rn(accx, accy);
}

// ---------------- launch ----------------

extern "C" void kernel_launch(void* const* d_in, const int* in_sizes, int n_in,
                              void* d_out, int out_size, void* d_ws, size_t ws_size,
                              hipStream_t stream) {
  const float* x   = (const float*)d_in[0];
  const int*   ei  = (const int*)d_in[1];
  const float* W1  = (const float*)d_in[2];
  const float* b1  = (const float*)d_in[3];
  const float* Wmu = (const float*)d_in[4];
  const float* bmu = (const float*)d_in[5];
  const float* Wls = (const float*)d_in[6];
  const float* bls = (const float*)d_in[7];

  int N = in_sizes[0] / 256;
  int E = in_sizes[1] / 2;
  const int* src = ei;
  const int* dst = ei + E;

  int NBINS = (N + 127) >> 7;          // 128 nodes per bin
  int NBLK  = (E + EPB - 1) / EPB;     // edge chunks (blocks)
  int NS    = NBINS * NBLK;            // hist matrix size

  char* ws = (char*)d_ws;
  size_t o = 0;
  auto alloc = [&](size_t b) { size_t c = o; o = (o + b + 511) & ~(size_t)511; return c; };
  int*   cnt     = (int*)(ws + alloc((size_t)N * 4));
  int*   rowptr  = (int*)(ws + alloc((size_t)N * 4));
  float* dinv    = (float*)(ws + alloc((size_t)N * 4));
  int*   bsum    = (int*)(ws + alloc(512));
  int*   histT   = (int*)(ws + alloc((size_t)NS * 4));
  int*   subPtr  = (int*)(ws + alloc((size_t)NS * 4));
  int*   col     = (int*)(ws + alloc((size_t)E * 4));
  int*   binned  = (int*)(ws + alloc((size_t)E * 4));
  __half* W1T  = (__half*)(ws + alloc(128 * 256 * 2));
  __half* WcT  = (__half*)(ws + alloc(256 * 128 * 2));
  float*  bcat = (float*)(ws + alloc(256 * 4));
  __half* h0   = (__half*)(ws + alloc((size_t)N * 128 * 2));  // GEMM1 out, later g
  __half* hBuf = (__half*)(ws + alloc((size_t)N * 128 * 2));  // h (relu'd)

  float* outMu = (float*)d_out;
  float* outLs = outMu + (size_t)N * 128;

  int nbScanN = (N + 1023) / 1024;
  int nbScanS = (NS + 1023) / 1024;

  // ---- CSR build (counting sort by bin, block-private windows) ----
  k_lhist<<<NBLK, 256, 0, stream>>>(dst, histT, E, NBLK, NBINS);
  k_blocksum<<<nbScanS, 256, 0, stream>>>(histT, bsum, NS);
  k_scan_bsum<<<1, 128, 0, stream>>>(bsum, nbScanS);
  k_scan_final<<<nbScanS, 256, 0, stream>>>(histT, bsum, subPtr, nullptr, NS);
  k_lscatter<<<NBLK, 256, 0, stream>>>(src, dst, subPtr, binned, E, NBLK, NBINS);
  k_bin_cnt<<<NBINS, 256, 0, stream>>>(binned, subPtr, cnt, E, NBLK, NBINS, N);
  k_blocksum<<<nbScanN, 256, 0, stream>>>(cnt, bsum, N);
  k_scan_bsum<<<1, 128, 0, stream>>>(bsum, nbScanN);
  k_scan_final<<<nbScanN, 256, 0, stream>>>(cnt, bsum, rowptr, dinv, N);
  k_bin_place<<<NBINS, 256, 0, stream>>>(binned, subPtr, rowptr, col, E, NBLK, NBINS, N);

  // ---- weights ----
  k_prep_w<<<(2 * 128 * 256 + 256 + 255) / 256, 256, 0, stream>>>(
      W1, Wmu, Wls, bmu, bls, W1T, WcT, bcat);

  int gx = (N + 127) / 128;
  // h0 = x @ W1                 [N,128] fp16
  k_gemm_mfma<0, 1><<<dim3(gx, 1), 256, 0, stream>>>(x, W1T, nullptr, h0, nullptr, N, 256, 0);
  // h = relu(A h0 + b1)         [N,128] fp16
  k_spmm_h<<<(N + 3) / 4, 256, 0, stream>>>(h0, rowptr, cnt, col, dinv, b1, hBuf, N, 1, 1);
  // g = A h                     [N,128] fp16 (reuse h0 buffer)
  k_spmm_h<<<(N + 3) / 4, 256, 0, stream>>>(hBuf, rowptr, cnt, col, dinv, nullptr, h0, N, 0, 0);
  // [mu | ls] = g @ [Wmu|Wls] + [bmu|bls]   one fused dispatch, grid.y=2
  k_gemm_mfma<1, 0><<<dim3(gx, 2), 256, 0, stream>>>(h0, WcT, bcat, outMu, outLs, N, 128, 1);
}